// Round 1
// baseline (362.277 us; speedup 1.0000x reference)
//
#include <hip/hip_runtime.h>
#include <math.h>

typedef unsigned short bf16u;
typedef __attribute__((ext_vector_type(8))) short short8;
typedef __attribute__((ext_vector_type(4))) float f32x4;

__device__ __forceinline__ bf16u f2bf(float f) {
    unsigned int u = __float_as_uint(f);
    u += 0x7fffu + ((u >> 16) & 1u);
    return (bf16u)(u >> 16);
}
__device__ __forceinline__ float bf2f(bf16u h) {
    return __uint_as_float(((unsigned int)h) << 16);
}

__device__ __forceinline__ void gload16(const void* g, void* s) {
    __builtin_amdgcn_global_load_lds((const __attribute__((address_space(1))) void*)g,
                                     (__attribute__((address_space(3))) void*)s, 16, 0, 0);
}

// ---------------------------------------------------------------------------
// Generic C = A @ B^T bf16 GEMM, 128x128 tile, 4 waves, 16x16x32 MFMA.
// A: (M x K) row-major bf16, B: (N x K) row-major bf16. lda = ldb = K.
// LDS is "fragment-major": element (rb, lane, j) at idx rb*512 + lane*8 + j
// holds tile element (row = rb*16 + (lane&15), k = (lane>>4)*8 + j).
// global_load_lds writes linearly (base + lane*16B); the global source address
// is pre-permuted so LDS lands fragment-major -> conflict-free ds_read_b128.
// EPI selects the epilogue / destination layout.
// ---------------------------------------------------------------------------
template<int EPI>
__global__ __launch_bounds__(256, 2) void gemm_bt(
    const bf16u* __restrict__ Aall, const bf16u* __restrict__ Ball, int K,
    long strideAz, long strideBz,
    bf16u* __restrict__ D0, bf16u* __restrict__ D1, bf16u* __restrict__ D2,
    float* __restrict__ Df, const float* __restrict__ bias, float scale)
{
    const int tid = threadIdx.x;
    const int l = tid & 63, w = tid >> 6;
    const int fr = l & 15, fq = l >> 4;     // fragment row / k-quarter
    const int kb = fq * 8;
    const int z = blockIdx.z;
    const bf16u* A = Aall + (long)z * strideAz;
    const bf16u* B = Ball + (long)z * strideBz;
    const int m0 = blockIdx.y * 128, n0 = blockIdx.x * 128;

    __shared__ __align__(16) bf16u As[4096];
    __shared__ __align__(16) bf16u Bs[4096];

    f32x4 acc[4][4];
#pragma unroll
    for (int i = 0; i < 4; ++i)
#pragma unroll
        for (int j = 0; j < 4; ++j) acc[i][j] = (f32x4){0.f, 0.f, 0.f, 0.f};

    // staging source offsets (elements) for the two 4KB halves each operand
    const long aoff0 = (long)(m0 + w * 16 + fr) * K + kb;
    const long aoff1 = (long)(m0 + (w + 4) * 16 + fr) * K + kb;
    const long boff0 = (long)(n0 + w * 16 + fr) * K + kb;
    const long boff1 = (long)(n0 + (w + 4) * 16 + fr) * K + kb;
    bf16u* asd0 = As + w * 512;
    bf16u* asd1 = As + w * 512 + 2048;
    bf16u* bsd0 = Bs + w * 512;
    bf16u* bsd1 = Bs + w * 512 + 2048;

    const int wr = w >> 1, wc = w & 1;      // wave -> 64x64 quadrant

    for (int k0 = 0; k0 < K; k0 += 32) {
        gload16(A + aoff0 + k0, asd0);
        gload16(A + aoff1 + k0, asd1);
        gload16(B + boff0 + k0, bsd0);
        gload16(B + boff1 + k0, bsd1);
        __syncthreads();                     // drains vmcnt before barrier

        short8 af[4], bg[4];
#pragma unroll
        for (int t = 0; t < 4; ++t) {
            af[t] = *(const short8*)(As + (wr * 4 + t) * 512 + l * 8);
            bg[t] = *(const short8*)(Bs + (wc * 4 + t) * 512 + l * 8);
        }
#pragma unroll
        for (int mt = 0; mt < 4; ++mt)
#pragma unroll
            for (int nt = 0; nt < 4; ++nt)
                acc[mt][nt] = __builtin_amdgcn_mfma_f32_16x16x32_bf16(
                    af[mt], bg[nt], acc[mt][nt], 0, 0, 0);
        __syncthreads();
    }

    // epilogue: element (mt,nt,reg): row = m0+wr*64+mt*16+fq*4+reg, col = n0+wc*64+nt*16+fr
#pragma unroll
    for (int mt = 0; mt < 4; ++mt) {
#pragma unroll
        for (int nt = 0; nt < 4; ++nt) {
            const f32x4 v = acc[mt][nt];
            const int col = n0 + wc * 64 + nt * 16 + fr;
            const int rbase = m0 + wr * 64 + mt * 16 + fq * 4;
#pragma unroll
            for (int r = 0; r < 4; ++r) {
                const float val = v[r];
                const int row = rbase + r;
                if constexpr (EPI == 1) {
                    // row = rr*1024 + i over (b*r, n); col in [0,1536): q|k|v
                    const int rr = row >> 10, i = row & 1023;
                    if (col < 512) {
                        const int h = col >> 6, d = col & 63;
                        D0[((long)(h * 1024 + i) << 11) + rr * 64 + d] = f2bf(val);
                    } else if (col < 1024) {
                        const int c = col - 512, h = c >> 6, d = c & 63;
                        D1[((long)(h * 1024 + i) << 11) + rr * 64 + d] = f2bf(val);
                    } else {
                        const int c = col - 1024, h = c >> 6, d = c & 63;
                        D2[((long)(h * 2048 + rr * 64 + d) << 10) + i] = f2bf(val);
                    }
                } else if constexpr (EPI == 2) {
                    // scaled logits, bf16, [h][i][j]
                    D0[((long)z << 20) + ((long)row << 10) + col] = f2bf(val * scale);
                } else if constexpr (EPI == 3) {
                    // out2[(rr*1024 + i)*512 + h*64 + d], col = rr*64+d
                    const int rb = col >> 6, d = col & 63;
                    D0[((long)(rb * 1024 + row) << 9) + z * 64 + d] = f2bf(val);
                } else {
                    // final fp32 + bias
                    Df[(long)row * 256 + col] = val + bias[col];
                }
            }
        }
    }
}

// x (fp32) -> bf16, 4 elems/thread
__global__ __launch_bounds__(256) void cvt_x(const float* __restrict__ in,
                                             bf16u* __restrict__ out) {
    const long idx = (long)(blockIdx.x * 256 + threadIdx.x) * 4;
    const float4 v = *(const float4*)(in + idx);
    ushort4 o;
    o.x = f2bf(v.x); o.y = f2bf(v.y); o.z = f2bf(v.z); o.w = f2bf(v.w);
    *(ushort4*)(out + idx) = o;
}

// out[c*R + r] = bf16(in[r*C + c])   (in: R x C fp32)
__global__ __launch_bounds__(256) void transpose_cvt(const float* __restrict__ in,
                                                     bf16u* __restrict__ out,
                                                     int R, int C) {
    const int idx = blockIdx.x * 256 + threadIdx.x;
    if (idx < R * C) {
        const int r = idx / C, c = idx % C;
        out[(long)c * R + r] = f2bf(in[idx]);
    }
}

// in-place row softmax over 1024 bf16 elements; one block per row
__global__ __launch_bounds__(256) void softmax_rows(bf16u* __restrict__ att) {
    const long base = (long)blockIdx.x << 10;
    const int tid = threadIdx.x;
    const uint2 u = *(const uint2*)(att + base + tid * 4);
    const float v0 = bf2f(u.x & 0xffffu), v1 = bf2f(u.x >> 16);
    const float v2 = bf2f(u.y & 0xffffu), v3 = bf2f(u.y >> 16);
    float m = fmaxf(fmaxf(v0, v1), fmaxf(v2, v3));
#pragma unroll
    for (int o = 32; o; o >>= 1) m = fmaxf(m, __shfl_xor(m, o));
    __shared__ float red[8];
    if ((tid & 63) == 0) red[tid >> 6] = m;
    __syncthreads();
    m = fmaxf(fmaxf(red[0], red[1]), fmaxf(red[2], red[3]));
    const float e0 = __expf(v0 - m), e1 = __expf(v1 - m);
    const float e2 = __expf(v2 - m), e3 = __expf(v3 - m);
    float s = e0 + e1 + e2 + e3;
#pragma unroll
    for (int o = 32; o; o >>= 1) s += __shfl_xor(s, o);
    if ((tid & 63) == 0) red[4 + (tid >> 6)] = s;
    __syncthreads();
    const float inv = 1.0f / (red[4] + red[5] + red[6] + red[7]);
    uint2 o2;
    o2.x = (unsigned)f2bf(e0 * inv) | ((unsigned)f2bf(e1 * inv) << 16);
    o2.y = (unsigned)f2bf(e2 * inv) | ((unsigned)f2bf(e3 * inv) << 16);
    *(uint2*)(att + base + tid * 4) = o2;
}

extern "C" void kernel_launch(void* const* d_in, const int* in_sizes, int n_in,
                              void* d_out, int out_size, void* d_ws, size_t ws_size,
                              hipStream_t stream) {
    (void)in_sizes; (void)n_in; (void)out_size; (void)ws_size;
    const float* x    = (const float*)d_in[0];
    const float* Wq   = (const float*)d_in[1];
    const float* Wkv  = (const float*)d_in[2];
    const float* Wout = (const float*)d_in[3];
    const float* bout = (const float*)d_in[4];
    float* out = (float*)d_out;

    char* ws = (char*)d_ws;
    bf16u* xb    = (bf16u*)(ws);                    // 32768 x 256        16.0 MB
    bf16u* WqkvT = (bf16u*)(ws + 16777216);         // 1536 x 256          0.75 MB
    bf16u* WoutT = (bf16u*)(ws + 17563648);         // 256 x 512           0.25 MB
    bf16u* Qt    = (bf16u*)(ws + 17825792);         // 8 x 1024 x 2048    32 MB
    bf16u* Kt    = (bf16u*)(ws + 51380224);         // 8 x 1024 x 2048    32 MB
    bf16u* Vt2   = (bf16u*)(ws + 84934656);         // 8 x 2048 x 1024    32 MB
    bf16u* att   = (bf16u*)(ws + 118489088);        // 8 x 1024 x 1024    16 MB
    bf16u* out2  = (bf16u*)(ws + 135266304);        // 32768 x 512        32 MB
    // total 168,820,736 bytes

    cvt_x<<<8192, 256, 0, stream>>>(x, xb);
    transpose_cvt<<<512, 256, 0, stream>>>(Wq, WqkvT, 256, 512);
    transpose_cvt<<<1024, 256, 0, stream>>>(Wkv, WqkvT + 512 * 256, 256, 1024);
    transpose_cvt<<<512, 256, 0, stream>>>(Wout, WoutT, 512, 256);

    const float scale = 1.0f / (8.0f * sqrtf(32.0f));

    // stage 1: qkv = xb @ WqkvT^T   (M=32768, N=1536, K=256), scatter to Qt/Kt/Vt2
    gemm_bt<1><<<dim3(12, 256, 1), 256, 0, stream>>>(
        xb, WqkvT, 256, 0, 0, Qt, Kt, Vt2, nullptr, nullptr, 0.f);

    // stage 2: per head, dots = Q_h @ K_h^T * scale  (M=N=1024, K=2048) -> att (bf16)
    gemm_bt<2><<<dim3(8, 8, 8), 256, 0, stream>>>(
        Qt, Kt, 2048, 1024L * 2048, 1024L * 2048, att, nullptr, nullptr, nullptr, nullptr, scale);

    softmax_rows<<<8192, 256, 0, stream>>>(att);

    // stage 3: per head, out = att_h @ Vt2_h^T (M=1024, N=2048, K=1024) -> out2
    gemm_bt<3><<<dim3(16, 8, 8), 256, 0, stream>>>(
        att, Vt2, 1024, 1024L * 1024, 2048L * 1024, out2, nullptr, nullptr, nullptr, nullptr, 0.f);

    // stage 4: final = out2 @ WoutT^T + bout  (M=32768, N=256, K=512) -> fp32 out
    gemm_bt<4><<<dim3(2, 256, 1), 256, 0, stream>>>(
        out2, WoutT, 512, 0, 0, nullptr, nullptr, nullptr, out, bout, 0.f);
}

// Round 2
// 316.509 us; speedup vs baseline: 1.1446x; 1.1446x over previous
//
#include <hip/hip_runtime.h>
#include <math.h>

typedef unsigned short bf16u;
typedef __attribute__((ext_vector_type(8))) short short8;
typedef __attribute__((ext_vector_type(4))) float f32x4;

__device__ __forceinline__ bf16u f2bf(float f) {
    unsigned int u = __float_as_uint(f);
    u += 0x7fffu + ((u >> 16) & 1u);
    return (bf16u)(u >> 16);
}
__device__ __forceinline__ float bf2f(bf16u h) {
    return __uint_as_float(((unsigned int)h) << 16);
}

__device__ __forceinline__ void gload16(const void* g, void* s) {
    __builtin_amdgcn_global_load_lds((const __attribute__((address_space(1))) void*)g,
                                     (__attribute__((address_space(3))) void*)s, 16, 0, 0);
}

// ---------------------------------------------------------------------------
// Generic C = A @ B^T bf16 GEMM, 128x128 tile, 4 waves, 16x16x32 MFMA.
// 2-phase double-buffered LDS: prefetch tile t+1 via global_load_lds before
// computing tile t; ONE barrier per K-step. LDS fragment-major so ds_read_b128
// is conflict-free. XCD-chunked block swizzle for L2 locality.
// ---------------------------------------------------------------------------
template<int EPI>
__global__ __launch_bounds__(256, 4) void gemm_bt(
    const bf16u* __restrict__ Aall, const bf16u* __restrict__ Ball, int K,
    long strideAz, long strideBz,
    bf16u* __restrict__ D0, bf16u* __restrict__ D1, bf16u* __restrict__ D2,
    float* __restrict__ Df, const float* __restrict__ bias, float scale)
{
    // ---- bijective XCD-chunked swizzle over the flattened grid ----
    const int gx = gridDim.x, gy = gridDim.y;
    const int nwg = gx * gy * gridDim.z;
    int flat = blockIdx.x + gx * (blockIdx.y + gy * blockIdx.z);
    int swz = (nwg & 7) ? flat : (flat & 7) * (nwg >> 3) + (flat >> 3);
    const int bx = swz % gx;
    const int t1 = swz / gx;
    const int by = t1 % gy;
    const int z  = t1 / gy;

    const int tid = threadIdx.x;
    const int l = tid & 63, w = tid >> 6;
    const int fr = l & 15, fq = l >> 4;     // fragment row / k-quarter
    const int kb = fq * 8;
    const bf16u* A = Aall + (long)z * strideAz;
    const bf16u* B = Ball + (long)z * strideBz;
    const int m0 = by * 128, n0 = bx * 128;

    // S: [As buf0 | As buf1 | Bs buf0 | Bs buf1], 4096 elems each = 32 KB
    __shared__ __align__(16) bf16u S[16384];

    f32x4 acc[4][4];
#pragma unroll
    for (int i = 0; i < 4; ++i)
#pragma unroll
        for (int j = 0; j < 4; ++j) acc[i][j] = (f32x4){0.f, 0.f, 0.f, 0.f};

    const long aoff0 = (long)(m0 + w * 16 + fr) * K + kb;
    const long aoff1 = (long)(m0 + (w + 4) * 16 + fr) * K + kb;
    const long boff0 = (long)(n0 + w * 16 + fr) * K + kb;
    const long boff1 = (long)(n0 + (w + 4) * 16 + fr) * K + kb;

    const int wr = w >> 1, wc = w & 1;      // wave -> 64x64 quadrant

#define STAGE(c, k0) do { \
        bf16u* as_ = S + (c) * 4096; \
        bf16u* bs_ = S + 8192 + (c) * 4096; \
        gload16(A + aoff0 + (k0), as_ + w * 512); \
        gload16(A + aoff1 + (k0), as_ + w * 512 + 2048); \
        gload16(B + boff0 + (k0), bs_ + w * 512); \
        gload16(B + boff1 + (k0), bs_ + w * 512 + 2048); \
    } while (0)

    STAGE(0, 0);
    __syncthreads();

    int cur = 0;
    for (int k0 = 0; k0 < K; k0 += 32) {
        if (k0 + 32 < K) STAGE(cur ^ 1, k0 + 32);   // prefetch next tile

        const bf16u* Ac = S + cur * 4096;
        const bf16u* Bc = S + 8192 + cur * 4096;
        short8 af[4], bg[4];
#pragma unroll
        for (int t = 0; t < 4; ++t) {
            af[t] = *(const short8*)(Ac + (wr * 4 + t) * 512 + l * 8);
            bg[t] = *(const short8*)(Bc + (wc * 4 + t) * 512 + l * 8);
        }
#pragma unroll
        for (int mt = 0; mt < 4; ++mt)
#pragma unroll
            for (int nt = 0; nt < 4; ++nt)
                acc[mt][nt] = __builtin_amdgcn_mfma_f32_16x16x32_bf16(
                    af[mt], bg[nt], acc[mt][nt], 0, 0, 0);
        __syncthreads();                            // drains vmcnt: next buf ready
        cur ^= 1;
    }
#undef STAGE

    // epilogue: element (mt,nt,reg): row = m0+wr*64+mt*16+fq*4+reg, col = n0+wc*64+nt*16+fr
    if constexpr (EPI == 1) {
        if (n0 >= 1024) {
            // ---- V blocks: transpose tile in LDS, write Vt2 coalesced ----
#pragma unroll
            for (int mt = 0; mt < 4; ++mt) {
#pragma unroll
                for (int nt = 0; nt < 4; ++nt) {
                    const f32x4 v = acc[mt][nt];
                    const int cl = wc * 64 + nt * 16 + fr;
                    const int rl = wr * 64 + mt * 16 + fq * 4;
                    ushort4 pk;
                    pk.x = f2bf(v[0]); pk.y = f2bf(v[1]);
                    pk.z = f2bf(v[2]); pk.w = f2bf(v[3]);
                    *(ushort4*)(S + cl * 128 + rl) = pk;   // transposed store
                }
            }
            __syncthreads();
            const int c2 = n0 - 1024;
            const int rr = m0 >> 10, i0 = m0 & 1023;
            const int rowt = tid >> 4, c0 = (tid & 15) * 8;
#pragma unroll
            for (int p = 0; p < 8; ++p) {
                const int row = p * 16 + rowt;            // hd index within tile
                const int col = c2 + row;
                const int h = col >> 6, d = col & 63;
                const short8 vv = *(const short8*)(S + row * 128 + c0);
                *(short8*)(D2 + ((long)(h * 2048 + rr * 64 + d) << 10) + i0 + c0) = vv;
            }
        } else {
            // ---- Q/K blocks: direct write (d-contiguous 32B chunks) ----
#pragma unroll
            for (int mt = 0; mt < 4; ++mt) {
#pragma unroll
                for (int nt = 0; nt < 4; ++nt) {
                    const f32x4 v = acc[mt][nt];
                    const int col = n0 + wc * 64 + nt * 16 + fr;
                    const int rbase = m0 + wr * 64 + mt * 16 + fq * 4;
#pragma unroll
                    for (int r = 0; r < 4; ++r) {
                        const float val = v[r];
                        const int row = rbase + r;
                        const int rr = row >> 10, i = row & 1023;
                        if (col < 512) {
                            const int h = col >> 6, d = col & 63;
                            D0[((long)(h * 1024 + i) << 11) + rr * 64 + d] = f2bf(val);
                        } else {
                            const int c = col - 512, h = c >> 6, d = c & 63;
                            D1[((long)(h * 1024 + i) << 11) + rr * 64 + d] = f2bf(val);
                        }
                    }
                }
            }
        }
    } else {
#pragma unroll
        for (int mt = 0; mt < 4; ++mt) {
#pragma unroll
            for (int nt = 0; nt < 4; ++nt) {
                const f32x4 v = acc[mt][nt];
                const int col = n0 + wc * 64 + nt * 16 + fr;
                const int rbase = m0 + wr * 64 + mt * 16 + fq * 4;
#pragma unroll
                for (int r = 0; r < 4; ++r) {
                    const float val = v[r];
                    const int row = rbase + r;
                    if constexpr (EPI == 2) {
                        D0[((long)z << 20) + ((long)row << 10) + col] = f2bf(val * scale);
                    } else if constexpr (EPI == 3) {
                        const int rb = col >> 6, d = col & 63;
                        D0[((long)(rb * 1024 + row) << 9) + z * 64 + d] = f2bf(val);
                    } else {
                        Df[(long)row * 256 + col] = val + bias[col];
                    }
                }
            }
        }
    }
}

// x (fp32) -> bf16, 4 elems/thread
__global__ __launch_bounds__(256) void cvt_x(const float* __restrict__ in,
                                             bf16u* __restrict__ out) {
    const long idx = (long)(blockIdx.x * 256 + threadIdx.x) * 4;
    const float4 v = *(const float4*)(in + idx);
    ushort4 o;
    o.x = f2bf(v.x); o.y = f2bf(v.y); o.z = f2bf(v.z); o.w = f2bf(v.w);
    *(ushort4*)(out + idx) = o;
}

// out[c*R + r] = bf16(in[r*C + c])   (in: R x C fp32)
__global__ __launch_bounds__(256) void transpose_cvt(const float* __restrict__ in,
                                                     bf16u* __restrict__ out,
                                                     int R, int C) {
    const int idx = blockIdx.x * 256 + threadIdx.x;
    if (idx < R * C) {
        const int r = idx / C, c = idx % C;
        out[(long)c * R + r] = f2bf(in[idx]);
    }
}

// in-place row softmax over 1024 bf16 elements; one block per row
__global__ __launch_bounds__(256) void softmax_rows(bf16u* __restrict__ att) {
    const long base = (long)blockIdx.x << 10;
    const int tid = threadIdx.x;
    const uint2 u = *(const uint2*)(att + base + tid * 4);
    const float v0 = bf2f(u.x & 0xffffu), v1 = bf2f(u.x >> 16);
    const float v2 = bf2f(u.y & 0xffffu), v3 = bf2f(u.y >> 16);
    float m = fmaxf(fmaxf(v0, v1), fmaxf(v2, v3));
#pragma unroll
    for (int o = 32; o; o >>= 1) m = fmaxf(m, __shfl_xor(m, o));
    __shared__ float red[8];
    if ((tid & 63) == 0) red[tid >> 6] = m;
    __syncthreads();
    m = fmaxf(fmaxf(red[0], red[1]), fmaxf(red[2], red[3]));
    const float e0 = __expf(v0 - m), e1 = __expf(v1 - m);
    const float e2 = __expf(v2 - m), e3 = __expf(v3 - m);
    float s = e0 + e1 + e2 + e3;
#pragma unroll
    for (int o = 32; o; o >>= 1) s += __shfl_xor(s, o);
    if ((tid & 63) == 0) red[4 + (tid >> 6)] = s;
    __syncthreads();
    const float inv = 1.0f / (red[4] + red[5] + red[6] + red[7]);
    uint2 o2;
    o2.x = (unsigned)f2bf(e0 * inv) | ((unsigned)f2bf(e1 * inv) << 16);
    o2.y = (unsigned)f2bf(e2 * inv) | ((unsigned)f2bf(e3 * inv) << 16);
    *(uint2*)(att + base + tid * 4) = o2;
}

extern "C" void kernel_launch(void* const* d_in, const int* in_sizes, int n_in,
                              void* d_out, int out_size, void* d_ws, size_t ws_size,
                              hipStream_t stream) {
    (void)in_sizes; (void)n_in; (void)out_size; (void)ws_size;
    const float* x    = (const float*)d_in[0];
    const float* Wq   = (const float*)d_in[1];
    const float* Wkv  = (const float*)d_in[2];
    const float* Wout = (const float*)d_in[3];
    const float* bout = (const float*)d_in[4];
    float* out = (float*)d_out;

    char* ws = (char*)d_ws;
    bf16u* xb    = (bf16u*)(ws);                    // 32768 x 256        16.0 MB
    bf16u* WqkvT = (bf16u*)(ws + 16777216);         // 1536 x 256          0.75 MB
    bf16u* WoutT = (bf16u*)(ws + 17563648);         // 256 x 512           0.25 MB
    bf16u* Qt    = (bf16u*)(ws + 17825792);         // 8 x 1024 x 2048    32 MB
    bf16u* Kt    = (bf16u*)(ws + 51380224);         // 8 x 1024 x 2048    32 MB
    bf16u* Vt2   = (bf16u*)(ws + 84934656);         // 8 x 2048 x 1024    32 MB
    bf16u* att   = (bf16u*)(ws + 118489088);        // 8 x 1024 x 1024    16 MB
    bf16u* out2  = (bf16u*)(ws + 135266304);        // 32768 x 512        32 MB
    // total 168,820,736 bytes

    cvt_x<<<8192, 256, 0, stream>>>(x, xb);
    transpose_cvt<<<512, 256, 0, stream>>>(Wq, WqkvT, 256, 512);
    transpose_cvt<<<1024, 256, 0, stream>>>(Wkv, WqkvT + 512 * 256, 256, 1024);
    transpose_cvt<<<512, 256, 0, stream>>>(Wout, WoutT, 512, 256);

    const float scale = 1.0f / (8.0f * sqrtf(32.0f));

    // stage 1: qkv = xb @ WqkvT^T   (M=32768, N=1536, K=256), scatter to Qt/Kt/Vt2
    gemm_bt<1><<<dim3(12, 256, 1), 256, 0, stream>>>(
        xb, WqkvT, 256, 0, 0, Qt, Kt, Vt2, nullptr, nullptr, 0.f);

    // stage 2: per head, dots = Q_h @ K_h^T * scale  (M=N=1024, K=2048) -> att (bf16)
    gemm_bt<2><<<dim3(8, 8, 8), 256, 0, stream>>>(
        Qt, Kt, 2048, 1024L * 2048, 1024L * 2048, att, nullptr, nullptr, nullptr, nullptr, scale);

    softmax_rows<<<8192, 256, 0, stream>>>(att);

    // stage 3: per head, out = att_h @ Vt2_h^T (M=1024, N=2048, K=1024) -> out2
    gemm_bt<3><<<dim3(16, 8, 8), 256, 0, stream>>>(
        att, Vt2, 1024, 1024L * 1024, 2048L * 1024, out2, nullptr, nullptr, nullptr, nullptr, 0.f);

    // stage 4: final = out2 @ WoutT^T + bout  (M=32768, N=256, K=512) -> fp32 out
    gemm_bt<4><<<dim3(2, 256, 1), 256, 0, stream>>>(
        out2, WoutT, 512, 0, 0, nullptr, nullptr, nullptr, out, bout, 0.f);
}

// Round 4
// 289.239 us; speedup vs baseline: 1.2525x; 1.0943x over previous
//
#include <hip/hip_runtime.h>
#include <math.h>

typedef unsigned short bf16u;
typedef __attribute__((ext_vector_type(8))) short short8;
typedef __attribute__((ext_vector_type(4))) float f32x4;

__device__ __forceinline__ bf16u f2bf(float f) {
    unsigned int u = __float_as_uint(f);
    u += 0x7fffu + ((u >> 16) & 1u);
    return (bf16u)(u >> 16);
}
__device__ __forceinline__ float bf2f(bf16u h) {
    return __uint_as_float(((unsigned int)h) << 16);
}

__device__ __forceinline__ void gload16(const void* g, void* s) {
    __builtin_amdgcn_global_load_lds((const __attribute__((address_space(1))) void*)g,
                                     (__attribute__((address_space(3))) void*)s, 16, 0, 0);
}

// ---------------------------------------------------------------------------
// 256x256 8-phase bf16 GEMM (C = A @ B^T), 8 waves (2M x 4N), BK=64.
// LDS fragment-major per K-tile (conflict-free ds_read_b128; linear
// global_load_lds dests, pre-permuted per-lane global source).
// Double buffer at K-tile granularity (2 x 64KB = 128KB LDS).
// RAW s_barrier (no implicit vmcnt drain) + counted vmcnt(4) checkpoints
// once per K-tile; vmcnt(0) only in the peeled last-but-one tile.
// Queue (half-tiles, 4 per K-tile, order B0,B1,A0,A1):
//   prologue: B0(0),B1(0),A0(0),A1(0),B0(1),B1(1)  -> vmcnt(4) -> barrier
//   KTILE(t): P1 stages A0(t+1), P2 A1(t+1), P3 B0(t+2), P4 B1(t+2)
// At KTILE(t) end vmcnt(4): outstanding = B(t+2) only; A(t+1),B(t+1) landed.
// B(t+2) writes tile-t's B region, whose reads retired at P2 (barrier-ordered).
// ---------------------------------------------------------------------------
#define MM(a_, b_, c_) c_ = __builtin_amdgcn_mfma_f32_16x16x32_bf16(a_, b_, c_, 0, 0, 0)
#define BAR() __builtin_amdgcn_s_barrier()

#define STG() do { if (q < nht) { \
    const int t_ = q >> 2, p_ = q & 3; \
    const bf16u* P_ = (p_ < 2) ? B : A; \
    const long s_ = ((p_ < 2) ? brow : arow) + ((p_ & 1) ? r128 : 0) + t_ * 64; \
    bf16u* d_ = S + ((t_ & 1) << 15) + ((p_ < 2) ? 16384 : 0) + ((p_ & 1) << 12) + (w << 9); \
    gload16(P_ + s_, d_); \
    gload16(P_ + s_ + 32, d_ + 8192); \
  } ++q; } while (0)

#define RDA(dst, t, m, kk) dst = *(const short8*)(S + (((t) & 1) << 15) + ((kk) << 13) + ((wr * 8 + (m)) << 9) + (l << 3))
#define RDB(dst, t, n, kk) dst = *(const short8*)(S + (((t) & 1) << 15) + 16384 + ((kk) << 13) + ((wc * 4 + (n)) << 9) + (l << 3))

#define KTILE(t, VMASM) do { \
  /* P1: A m0-3 (8 rd), B n0-1 (4 rd) */ \
  RDA(af[0][0],t,0,0); RDA(af[0][1],t,0,1); RDA(af[1][0],t,1,0); RDA(af[1][1],t,1,1); \
  RDA(af[2][0],t,2,0); RDA(af[2][1],t,2,1); RDA(af[3][0],t,3,0); RDA(af[3][1],t,3,1); \
  RDB(b0[0][0],t,0,0); RDB(b0[0][1],t,0,1); RDB(b0[1][0],t,1,0); RDB(b0[1][1],t,1,1); \
  STG(); \
  BAR(); \
  __builtin_amdgcn_s_setprio(1); \
  MM(af[0][0],b0[0][0],acc[0][0]); MM(af[0][1],b0[0][1],acc[0][0]); \
  MM(af[0][0],b0[1][0],acc[0][1]); MM(af[0][1],b0[1][1],acc[0][1]); \
  MM(af[1][0],b0[0][0],acc[1][0]); MM(af[1][1],b0[0][1],acc[1][0]); \
  MM(af[1][0],b0[1][0],acc[1][1]); MM(af[1][1],b0[1][1],acc[1][1]); \
  MM(af[2][0],b0[0][0],acc[2][0]); MM(af[2][1],b0[0][1],acc[2][0]); \
  MM(af[2][0],b0[1][0],acc[2][1]); MM(af[2][1],b0[1][1],acc[2][1]); \
  MM(af[3][0],b0[0][0],acc[3][0]); MM(af[3][1],b0[0][1],acc[3][0]); \
  MM(af[3][0],b0[1][0],acc[3][1]); MM(af[3][1],b0[1][1],acc[3][1]); \
  __builtin_amdgcn_s_setprio(0); \
  BAR(); \
  /* P2: B n2-3 (4 rd) */ \
  RDB(b1[0][0],t,2,0); RDB(b1[0][1],t,2,1); RDB(b1[1][0],t,3,0); RDB(b1[1][1],t,3,1); \
  STG(); \
  BAR(); \
  __builtin_amdgcn_s_setprio(1); \
  MM(af[0][0],b1[0][0],acc[0][2]); MM(af[0][1],b1[0][1],acc[0][2]); \
  MM(af[0][0],b1[1][0],acc[0][3]); MM(af[0][1],b1[1][1],acc[0][3]); \
  MM(af[1][0],b1[0][0],acc[1][2]); MM(af[1][1],b1[0][1],acc[1][2]); \
  MM(af[1][0],b1[1][0],acc[1][3]); MM(af[1][1],b1[1][1],acc[1][3]); \
  MM(af[2][0],b1[0][0],acc[2][2]); MM(af[2][1],b1[0][1],acc[2][2]); \
  MM(af[2][0],b1[1][0],acc[2][3]); MM(af[2][1],b1[1][1],acc[2][3]); \
  MM(af[3][0],b1[0][0],acc[3][2]); MM(af[3][1],b1[0][1],acc[3][2]); \
  MM(af[3][0],b1[1][0],acc[3][3]); MM(af[3][1],b1[1][1],acc[3][3]); \
  __builtin_amdgcn_s_setprio(0); \
  BAR(); \
  /* P3: A m4-7 (8 rd, reuse af) */ \
  RDA(af[0][0],t,4,0); RDA(af[0][1],t,4,1); RDA(af[1][0],t,5,0); RDA(af[1][1],t,5,1); \
  RDA(af[2][0],t,6,0); RDA(af[2][1],t,6,1); RDA(af[3][0],t,7,0); RDA(af[3][1],t,7,1); \
  STG(); \
  BAR(); \
  __builtin_amdgcn_s_setprio(1); \
  MM(af[0][0],b1[0][0],acc[4][2]); MM(af[0][1],b1[0][1],acc[4][2]); \
  MM(af[0][0],b1[1][0],acc[4][3]); MM(af[0][1],b1[1][1],acc[4][3]); \
  MM(af[1][0],b1[0][0],acc[5][2]); MM(af[1][1],b1[0][1],acc[5][2]); \
  MM(af[1][0],b1[1][0],acc[5][3]); MM(af[1][1],b1[1][1],acc[5][3]); \
  MM(af[2][0],b1[0][0],acc[6][2]); MM(af[2][1],b1[0][1],acc[6][2]); \
  MM(af[2][0],b1[1][0],acc[6][3]); MM(af[2][1],b1[1][1],acc[6][3]); \
  MM(af[3][0],b1[0][0],acc[7][2]); MM(af[3][1],b1[0][1],acc[7][2]); \
  MM(af[3][0],b1[1][0],acc[7][3]); MM(af[3][1],b1[1][1],acc[7][3]); \
  __builtin_amdgcn_s_setprio(0); \
  BAR(); \
  /* P4: no reads; b0 + new af still live */ \
  STG(); \
  BAR(); \
  __builtin_amdgcn_s_setprio(1); \
  MM(af[0][0],b0[0][0],acc[4][0]); MM(af[0][1],b0[0][1],acc[4][0]); \
  MM(af[0][0],b0[1][0],acc[4][1]); MM(af[0][1],b0[1][1],acc[4][1]); \
  MM(af[1][0],b0[0][0],acc[5][0]); MM(af[1][1],b0[0][1],acc[5][0]); \
  MM(af[1][0],b0[1][0],acc[5][1]); MM(af[1][1],b0[1][1],acc[5][1]); \
  MM(af[2][0],b0[0][0],acc[6][0]); MM(af[2][1],b0[0][1],acc[6][0]); \
  MM(af[2][0],b0[1][0],acc[6][1]); MM(af[2][1],b0[1][1],acc[6][1]); \
  MM(af[3][0],b0[0][0],acc[7][0]); MM(af[3][1],b0[0][1],acc[7][0]); \
  MM(af[3][0],b0[1][0],acc[7][1]); MM(af[3][1],b0[1][1],acc[7][1]); \
  __builtin_amdgcn_s_setprio(0); \
  VMASM; \
  BAR(); \
} while (0)

template<int EPI>
__global__ __launch_bounds__(512, 2) void gemm8(
    const bf16u* __restrict__ Aall, const bf16u* __restrict__ Ball, int K,
    long sAz, long sBz,
    bf16u* __restrict__ D0, bf16u* __restrict__ D1, bf16u* __restrict__ D2,
    float* __restrict__ Df, const float* __restrict__ bias, float scale)
{
    // bijective XCD-chunked swizzle over flattened grid (all grids %8==0)
    const int gx = gridDim.x, gy = gridDim.y;
    const int nwg = gx * gy * gridDim.z;
    int flat = blockIdx.x + gx * (blockIdx.y + gy * blockIdx.z);
    int swz = (nwg & 7) ? flat : (flat & 7) * (nwg >> 3) + (flat >> 3);
    const int bx = swz % gx;
    int tq = swz / gx;
    const int by = tq % gy;
    const int z = tq / gy;

    const int tid = threadIdx.x;
    const int l = tid & 63, w = tid >> 6;
    const int fr = l & 15, fq = l >> 4;
    const int wr = w >> 2, wc = w & 3;      // 2M x 4N wave grid
    const bf16u* A = Aall + (long)z * sAz;
    const bf16u* B = Ball + (long)z * sBz;
    const int m0 = by << 8, n0 = bx << 8;

    __shared__ __align__(16) bf16u S[65536];   // 128 KB

    f32x4 acc[8][4];
#pragma unroll
    for (int i = 0; i < 8; ++i)
#pragma unroll
        for (int j = 0; j < 4; ++j) acc[i][j] = (f32x4){0.f, 0.f, 0.f, 0.f};

    const int NT = K >> 6;         // K-tiles of 64 (always even here)
    const int nht = NT << 2;       // half-tile queue length
    const int NI = NT >> 1;        // iterations (2 K-tiles each)
    int q = 0;

    const long arow = (long)(m0 + w * 16 + fr) * K + fq * 8;
    const long brow = (long)(n0 + w * 16 + fr) * K + fq * 8;
    const long r128 = (long)128 * K;

    // prologue: tile0 full + tile1 B0,B1
    STG(); STG(); STG(); STG(); STG(); STG();
    asm volatile("s_waitcnt vmcnt(4)" ::: "memory");
    BAR();

    short8 af[4][2], b0[2][2], b1[2][2];

    for (int i = 0; i < NI - 1; ++i) {
        KTILE(2 * i,     asm volatile("s_waitcnt vmcnt(4)" ::: "memory"));
        KTILE(2 * i + 1, asm volatile("s_waitcnt vmcnt(4)" ::: "memory"));
    }
    KTILE(2 * NI - 2, asm volatile("s_waitcnt vmcnt(0)" ::: "memory"));
    KTILE(2 * NI - 1, (void)0);

    // ---- epilogue ----
    const int colb = n0 + wc * 64;
    const int rowb = m0 + wr * 128;
    if constexpr (EPI == 1) {
        if (n0 >= 1024) {
            // V blocks: transpose 256x256 tile in S, write Vt2 coalesced
            __syncthreads();
#pragma unroll
            for (int m = 0; m < 8; ++m)
#pragma unroll
                for (int n = 0; n < 4; ++n) {
                    const int cl = wc * 64 + n * 16 + fr;
                    const int rl = wr * 128 + m * 16 + fq * 4;
                    ushort4 pk;
                    pk.x = f2bf(acc[m][n][0]); pk.y = f2bf(acc[m][n][1]);
                    pk.z = f2bf(acc[m][n][2]); pk.w = f2bf(acc[m][n][3]);
                    *(ushort4*)(S + cl * 256 + rl) = pk;
                }
            __syncthreads();
            const int c2 = n0 - 1024;
            const int rr = m0 >> 10, i0 = m0 & 1023;
            const int rowt = tid >> 5;          // 0..15
            const int c0 = (tid & 31) * 8;      // 0..248, full coverage
#pragma unroll
            for (int p = 0; p < 16; ++p) {
                const int row = p * 16 + rowt;  // transposed row = v-channel
                const int hd = c2 + row;
                const int h = hd >> 6, d = hd & 63;
                *(short8*)(D2 + (((long)(h * 2048 + rr * 64 + d)) << 10) + i0 + c0)
                    = *(const short8*)(S + row * 256 + c0);
            }
        } else {
#pragma unroll
            for (int m = 0; m < 8; ++m)
#pragma unroll
                for (int n = 0; n < 4; ++n) {
                    const int col = colb + n * 16 + fr;
                    const int rb = rowb + m * 16 + fq * 4;
#pragma unroll
                    for (int r = 0; r < 4; ++r) {
                        const int row = rb + r;
                        const int rr = row >> 10, i = row & 1023;
                        const float val = acc[m][n][r];
                        if (col < 512) {
                            const int h = col >> 6, d = col & 63;
                            D0[((long)(h * 1024 + i) << 11) + rr * 64 + d] = f2bf(val);
                        } else {
                            const int c = col - 512, h = c >> 6, d = c & 63;
                            D1[((long)(h * 1024 + i) << 11) + rr * 64 + d] = f2bf(val);
                        }
                    }
                }
        }
    } else if constexpr (EPI == 2) {
#pragma unroll
        for (int m = 0; m < 8; ++m)
#pragma unroll
            for (int n = 0; n < 4; ++n) {
                const int col = colb + n * 16 + fr;
                const int rb = rowb + m * 16 + fq * 4;
#pragma unroll
                for (int r = 0; r < 4; ++r)
                    D0[((long)z << 20) + ((long)(rb + r) << 10) + col] = f2bf(acc[m][n][r] * scale);
            }
    } else if constexpr (EPI == 3) {
#pragma unroll
        for (int m = 0; m < 8; ++m)
#pragma unroll
            for (int n = 0; n < 4; ++n) {
                const int col = colb + n * 16 + fr;
                const int cb = col >> 6, d = col & 63;
                const int rb = rowb + m * 16 + fq * 4;
#pragma unroll
                for (int r = 0; r < 4; ++r)
                    D0[((long)(cb * 1024 + rb + r) << 9) + z * 64 + d] = f2bf(acc[m][n][r]);
            }
    } else {
#pragma unroll
        for (int m = 0; m < 8; ++m)
#pragma unroll
            for (int n = 0; n < 4; ++n) {
                const int col = colb + n * 16 + fr;
                const int rb = rowb + m * 16 + fq * 4;
#pragma unroll
                for (int r = 0; r < 4; ++r)
                    Df[(long)(rb + r) * 256 + col] = acc[m][n][r] + bias[col];
            }
    }
}

// x (fp32) -> bf16, 4 elems/thread
__global__ __launch_bounds__(256) void cvt_x(const float* __restrict__ in,
                                             bf16u* __restrict__ out) {
    const long idx = (long)(blockIdx.x * 256 + threadIdx.x) * 4;
    const float4 v = *(const float4*)(in + idx);
    ushort4 o;
    o.x = f2bf(v.x); o.y = f2bf(v.y); o.z = f2bf(v.z); o.w = f2bf(v.w);
    *(ushort4*)(out + idx) = o;
}

// out[c*R + r] = bf16(in[r*C + c])   (in: R x C fp32)
__global__ __launch_bounds__(256) void transpose_cvt(const float* __restrict__ in,
                                                     bf16u* __restrict__ out,
                                                     int R, int C) {
    const int idx = blockIdx.x * 256 + threadIdx.x;
    if (idx < R * C) {
        const int r = idx / C, c = idx % C;
        out[(long)c * R + r] = f2bf(in[idx]);
    }
}

// in-place row softmax over 1024 bf16 elements; one block per row
__global__ __launch_bounds__(256) void softmax_rows(bf16u* __restrict__ att) {
    const long base = (long)blockIdx.x << 10;
    const int tid = threadIdx.x;
    const uint2 u = *(const uint2*)(att + base + tid * 4);
    const float v0 = bf2f(u.x & 0xffffu), v1 = bf2f(u.x >> 16);
    const float v2 = bf2f(u.y & 0xffffu), v3 = bf2f(u.y >> 16);
    float m = fmaxf(fmaxf(v0, v1), fmaxf(v2, v3));
#pragma unroll
    for (int o = 32; o; o >>= 1) m = fmaxf(m, __shfl_xor(m, o));
    __shared__ float red[8];
    if ((tid & 63) == 0) red[tid >> 6] = m;
    __syncthreads();
    m = fmaxf(fmaxf(red[0], red[1]), fmaxf(red[2], red[3]));
    const float e0 = __expf(v0 - m), e1 = __expf(v1 - m);
    const float e2 = __expf(v2 - m), e3 = __expf(v3 - m);
    float s = e0 + e1 + e2 + e3;
#pragma unroll
    for (int o = 32; o; o >>= 1) s += __shfl_xor(s, o);
    if ((tid & 63) == 0) red[4 + (tid >> 6)] = s;
    __syncthreads();
    const float inv = 1.0f / (red[4] + red[5] + red[6] + red[7]);
    uint2 o2;
    o2.x = (unsigned)f2bf(e0 * inv) | ((unsigned)f2bf(e1 * inv) << 16);
    o2.y = (unsigned)f2bf(e2 * inv) | ((unsigned)f2bf(e3 * inv) << 16);
    *(uint2*)(att + base + tid * 4) = o2;
}

extern "C" void kernel_launch(void* const* d_in, const int* in_sizes, int n_in,
                              void* d_out, int out_size, void* d_ws, size_t ws_size,
                              hipStream_t stream) {
    (void)in_sizes; (void)n_in; (void)out_size; (void)ws_size;
    const float* x    = (const float*)d_in[0];
    const float* Wq   = (const float*)d_in[1];
    const float* Wkv  = (const float*)d_in[2];
    const float* Wout = (const float*)d_in[3];
    const float* bout = (const float*)d_in[4];
    float* out = (float*)d_out;

    char* ws = (char*)d_ws;
    bf16u* xb    = (bf16u*)(ws);                    // 32768 x 256        16.0 MB
    bf16u* WqkvT = (bf16u*)(ws + 16777216);         // 1536 x 256          0.75 MB
    bf16u* WoutT = (bf16u*)(ws + 17563648);         // 256 x 512           0.25 MB
    bf16u* Qt    = (bf16u*)(ws + 17825792);         // 8 x 1024 x 2048    32 MB
    bf16u* Kt    = (bf16u*)(ws + 51380224);         // 8 x 1024 x 2048    32 MB
    bf16u* Vt2   = (bf16u*)(ws + 84934656);         // 8 x 2048 x 1024    32 MB
    bf16u* att   = (bf16u*)(ws + 118489088);        // 8 x 1024 x 1024    16 MB
    bf16u* out2  = (bf16u*)(ws + 135266304);        // 32768 x 512        32 MB
    // total 168,820,736 bytes

    cvt_x<<<8192, 256, 0, stream>>>(x, xb);
    transpose_cvt<<<512, 256, 0, stream>>>(Wq, WqkvT, 256, 512);
    transpose_cvt<<<1024, 256, 0, stream>>>(Wkv, WqkvT + 512 * 256, 256, 1024);
    transpose_cvt<<<512, 256, 0, stream>>>(Wout, WoutT, 512, 256);

    const float scale = 1.0f / (8.0f * sqrtf(32.0f));

    // stage 1: qkv = xb @ WqkvT^T   (M=32768, N=1536, K=256) -> Qt/Kt/Vt2
    gemm8<1><<<dim3(6, 128, 1), 512, 0, stream>>>(
        xb, WqkvT, 256, 0, 0, Qt, Kt, Vt2, nullptr, nullptr, 0.f);

    // stage 2: per head, dots = Q_h @ K_h^T * scale  (M=N=1024, K=2048) -> att
    gemm8<2><<<dim3(4, 4, 8), 512, 0, stream>>>(
        Qt, Kt, 2048, 1024L * 2048, 1024L * 2048, att, nullptr, nullptr, nullptr, nullptr, scale);

    softmax_rows<<<8192, 256, 0, stream>>>(att);

    // stage 3: per head, out = att_h @ Vt2_h^T (M=1024, N=2048, K=1024) -> out2
    gemm8<3><<<dim3(8, 4, 8), 512, 0, stream>>>(
        att, Vt2, 1024, 1024L * 1024, 2048L * 1024, out2, nullptr, nullptr, nullptr, nullptr, 0.f);

    // stage 4: final = out2 @ WoutT^T + bout  (M=32768, N=256, K=512) -> fp32 out
    gemm8<4><<<dim3(1, 128, 1), 512, 0, stream>>>(
        out2, WoutT, 512, 0, 0, nullptr, nullptr, nullptr, out, bout, 0.f);
}

// Round 7
// 267.900 us; speedup vs baseline: 1.3523x; 1.0797x over previous
//
#include <hip/hip_runtime.h>
#include <math.h>

typedef unsigned short bf16u;
typedef __attribute__((ext_vector_type(8))) short short8;
typedef __attribute__((ext_vector_type(4))) float f32x4;

__device__ __forceinline__ bf16u f2bf(float f) {
    unsigned int u = __float_as_uint(f);
    u += 0x7fffu + ((u >> 16) & 1u);
    return (bf16u)(u >> 16);
}
__device__ __forceinline__ float bf2f(bf16u h) {
    return __uint_as_float(((unsigned int)h) << 16);
}

__device__ __forceinline__ void gload16(const void* g, void* s) {
    __builtin_amdgcn_global_load_lds((const __attribute__((address_space(1))) void*)g,
                                     (__attribute__((address_space(3))) void*)s, 16, 0, 0);
}

// ---------------------------------------------------------------------------
// 2-phase 128x128 bf16 GEMM (C = A @ B^T), 4 waves, double-buffered LDS,
// fragment-major (conflict-free). Used for stage 1 (short K, high occupancy)
// and stage 4 (N=256 needs 128-wide tiles for a full-machine grid).
// ---------------------------------------------------------------------------
template<int EPI>
__global__ __launch_bounds__(256, 4) void gemm_bt(
    const bf16u* __restrict__ Aall, const bf16u* __restrict__ Ball, int K,
    long strideAz, long strideBz,
    bf16u* __restrict__ D0, bf16u* __restrict__ D1, bf16u* __restrict__ D2,
    float* __restrict__ Df, const float* __restrict__ bias, float scale)
{
    // bijective XCD-chunked swizzle over the flattened grid
    const int gx = gridDim.x, gy = gridDim.y;
    const int nwg = gx * gy * gridDim.z;
    int flat = blockIdx.x + gx * (blockIdx.y + gy * blockIdx.z);
    int swz = (nwg & 7) ? flat : (flat & 7) * (nwg >> 3) + (flat >> 3);
    const int bx = swz % gx;
    const int t1 = swz / gx;
    const int by = t1 % gy;
    const int z  = t1 / gy;

    const int tid = threadIdx.x;
    const int l = tid & 63, w = tid >> 6;
    const int fr = l & 15, fq = l >> 4;
    const int kb = fq * 8;
    const bf16u* A = Aall + (long)z * strideAz;
    const bf16u* B = Ball + (long)z * strideBz;
    const int m0 = by * 128, n0 = bx * 128;

    __shared__ __align__(16) bf16u S[16384];

    f32x4 acc[4][4];
#pragma unroll
    for (int i = 0; i < 4; ++i)
#pragma unroll
        for (int j = 0; j < 4; ++j) acc[i][j] = (f32x4){0.f, 0.f, 0.f, 0.f};

    const long aoff0 = (long)(m0 + w * 16 + fr) * K + kb;
    const long aoff1 = (long)(m0 + (w + 4) * 16 + fr) * K + kb;
    const long boff0 = (long)(n0 + w * 16 + fr) * K + kb;
    const long boff1 = (long)(n0 + (w + 4) * 16 + fr) * K + kb;

    const int wr = w >> 1, wc = w & 1;

#define STAGE(c, k0) do { \
        bf16u* as_ = S + (c) * 4096; \
        bf16u* bs_ = S + 8192 + (c) * 4096; \
        gload16(A + aoff0 + (k0), as_ + w * 512); \
        gload16(A + aoff1 + (k0), as_ + w * 512 + 2048); \
        gload16(B + boff0 + (k0), bs_ + w * 512); \
        gload16(B + boff1 + (k0), bs_ + w * 512 + 2048); \
    } while (0)

    STAGE(0, 0);
    __syncthreads();

    int cur = 0;
    for (int k0 = 0; k0 < K; k0 += 32) {
        if (k0 + 32 < K) STAGE(cur ^ 1, k0 + 32);

        const bf16u* Ac = S + cur * 4096;
        const bf16u* Bc = S + 8192 + cur * 4096;
        short8 af[4], bg[4];
#pragma unroll
        for (int t = 0; t < 4; ++t) {
            af[t] = *(const short8*)(Ac + (wr * 4 + t) * 512 + l * 8);
            bg[t] = *(const short8*)(Bc + (wc * 4 + t) * 512 + l * 8);
        }
#pragma unroll
        for (int mt = 0; mt < 4; ++mt)
#pragma unroll
            for (int nt = 0; nt < 4; ++nt)
                acc[mt][nt] = __builtin_amdgcn_mfma_f32_16x16x32_bf16(
                    af[mt], bg[nt], acc[mt][nt], 0, 0, 0);
        __syncthreads();
        cur ^= 1;
    }
#undef STAGE

    if constexpr (EPI == 1) {
        if (n0 >= 1024) {
            // V blocks: transpose tile in LDS, write Vt2 coalesced
#pragma unroll
            for (int mt = 0; mt < 4; ++mt) {
#pragma unroll
                for (int nt = 0; nt < 4; ++nt) {
                    const f32x4 v = acc[mt][nt];
                    const int cl = wc * 64 + nt * 16 + fr;
                    const int rl = wr * 64 + mt * 16 + fq * 4;
                    ushort4 pk;
                    pk.x = f2bf(v[0]); pk.y = f2bf(v[1]);
                    pk.z = f2bf(v[2]); pk.w = f2bf(v[3]);
                    *(ushort4*)(S + cl * 128 + rl) = pk;
                }
            }
            __syncthreads();
            const int c2 = n0 - 1024;
            const int rr = m0 >> 10, i0 = m0 & 1023;
            const int rowt = tid >> 4, c0 = (tid & 15) * 8;
#pragma unroll
            for (int p = 0; p < 8; ++p) {
                const int row = p * 16 + rowt;
                const int col = c2 + row;
                const int h = col >> 6, d = col & 63;
                const short8 vv = *(const short8*)(S + row * 128 + c0);
                *(short8*)(D2 + ((long)(h * 2048 + rr * 64 + d) << 10) + i0 + c0) = vv;
            }
        } else {
#pragma unroll
            for (int mt = 0; mt < 4; ++mt) {
#pragma unroll
                for (int nt = 0; nt < 4; ++nt) {
                    const f32x4 v = acc[mt][nt];
                    const int col = n0 + wc * 64 + nt * 16 + fr;
                    const int rbase = m0 + wr * 64 + mt * 16 + fq * 4;
#pragma unroll
                    for (int r = 0; r < 4; ++r) {
                        const float val = v[r];
                        const int row = rbase + r;
                        const int rr = row >> 10, i = row & 1023;
                        if (col < 512) {
                            const int h = col >> 6, d = col & 63;
                            D0[((long)(h * 1024 + i) << 11) + rr * 64 + d] = f2bf(val);
                        } else {
                            const int c = col - 512, h = c >> 6, d = c & 63;
                            D1[((long)(h * 1024 + i) << 11) + rr * 64 + d] = f2bf(val);
                        }
                    }
                }
            }
        }
    } else {
#pragma unroll
        for (int mt = 0; mt < 4; ++mt) {
#pragma unroll
            for (int nt = 0; nt < 4; ++nt) {
                const f32x4 v = acc[mt][nt];
                const int col = n0 + wc * 64 + nt * 16 + fr;
                const int rbase = m0 + wr * 64 + mt * 16 + fq * 4;
#pragma unroll
                for (int r = 0; r < 4; ++r)
                    Df[(long)(rbase + r) * 256 + col] = v[r] + bias[col];
            }
        }
    }
}

// ---------------------------------------------------------------------------
// 256x256 8-phase bf16 GEMM (C = A @ B^T), 8 waves (2M x 4N), BK=64.
// RAW s_barrier + counted vmcnt(4) checkpoints (verified R4 schedule).
// Kld = row stride; Kloop = contracted length; splitOff = per-(z>>3) K offset
// (split-K: z&7 selects head, z>>3 selects K-half). EPI=2: scaled bf16
// partial logits [z][i][j]; EPI=3: PV output scatter.
// ---------------------------------------------------------------------------
#define MM(a_, b_, c_) c_ = __builtin_amdgcn_mfma_f32_16x16x32_bf16(a_, b_, c_, 0, 0, 0)
#define BAR() __builtin_amdgcn_s_barrier()

#define STG() do { if (q < nht) { \
    const int t_ = q >> 2, p_ = q & 3; \
    const bf16u* P_ = (p_ < 2) ? B : A; \
    const long s_ = ((p_ < 2) ? brow : arow) + ((p_ & 1) ? r128 : 0) + t_ * 64; \
    bf16u* d_ = S + ((t_ & 1) << 15) + ((p_ < 2) ? 16384 : 0) + ((p_ & 1) << 12) + (w << 9); \
    gload16(P_ + s_, d_); \
    gload16(P_ + s_ + 32, d_ + 8192); \
  } ++q; } while (0)

#define RDA(dst, t, m, kk) dst = *(const short8*)(S + (((t) & 1) << 15) + ((kk) << 13) + ((wr * 8 + (m)) << 9) + (l << 3))
#define RDB(dst, t, n, kk) dst = *(const short8*)(S + (((t) & 1) << 15) + 16384 + ((kk) << 13) + ((wc * 4 + (n)) << 9) + (l << 3))

#define KTILE(t, VMASM) do { \
  RDA(af[0][0],t,0,0); RDA(af[0][1],t,0,1); RDA(af[1][0],t,1,0); RDA(af[1][1],t,1,1); \
  RDA(af[2][0],t,2,0); RDA(af[2][1],t,2,1); RDA(af[3][0],t,3,0); RDA(af[3][1],t,3,1); \
  RDB(b0[0][0],t,0,0); RDB(b0[0][1],t,0,1); RDB(b0[1][0],t,1,0); RDB(b0[1][1],t,1,1); \
  STG(); \
  BAR(); \
  __builtin_amdgcn_s_setprio(1); \
  MM(af[0][0],b0[0][0],acc[0][0]); MM(af[0][1],b0[0][1],acc[0][0]); \
  MM(af[0][0],b0[1][0],acc[0][1]); MM(af[0][1],b0[1][1],acc[0][1]); \
  MM(af[1][0],b0[0][0],acc[1][0]); MM(af[1][1],b0[0][1],acc[1][0]); \
  MM(af[1][0],b0[1][0],acc[1][1]); MM(af[1][1],b0[1][1],acc[1][1]); \
  MM(af[2][0],b0[0][0],acc[2][0]); MM(af[2][1],b0[0][1],acc[2][0]); \
  MM(af[2][0],b0[1][0],acc[2][1]); MM(af[2][1],b0[1][1],acc[2][1]); \
  MM(af[3][0],b0[0][0],acc[3][0]); MM(af[3][1],b0[0][1],acc[3][0]); \
  MM(af[3][0],b0[1][0],acc[3][1]); MM(af[3][1],b0[1][1],acc[3][1]); \
  __builtin_amdgcn_s_setprio(0); \
  BAR(); \
  RDB(b1[0][0],t,2,0); RDB(b1[0][1],t,2,1); RDB(b1[1][0],t,3,0); RDB(b1[1][1],t,3,1); \
  STG(); \
  BAR(); \
  __builtin_amdgcn_s_setprio(1); \
  MM(af[0][0],b1[0][0],acc[0][2]); MM(af[0][1],b1[0][1],acc[0][2]); \
  MM(af[0][0],b1[1][0],acc[0][3]); MM(af[0][1],b1[1][1],acc[0][3]); \
  MM(af[1][0],b1[0][0],acc[1][2]); MM(af[1][1],b1[0][1],acc[1][2]); \
  MM(af[1][0],b1[1][0],acc[1][3]); MM(af[1][1],b1[1][1],acc[1][3]); \
  MM(af[2][0],b1[0][0],acc[2][2]); MM(af[2][1],b1[0][1],acc[2][2]); \
  MM(af[2][0],b1[1][0],acc[2][3]); MM(af[2][1],b1[1][1],acc[2][3]); \
  MM(af[3][0],b1[0][0],acc[3][2]); MM(af[3][1],b1[0][1],acc[3][2]); \
  MM(af[3][0],b1[1][0],acc[3][3]); MM(af[3][1],b1[1][1],acc[3][3]); \
  __builtin_amdgcn_s_setprio(0); \
  BAR(); \
  RDA(af[0][0],t,4,0); RDA(af[0][1],t,4,1); RDA(af[1][0],t,5,0); RDA(af[1][1],t,5,1); \
  RDA(af[2][0],t,6,0); RDA(af[2][1],t,6,1); RDA(af[3][0],t,7,0); RDA(af[3][1],t,7,1); \
  STG(); \
  BAR(); \
  __builtin_amdgcn_s_setprio(1); \
  MM(af[0][0],b1[0][0],acc[4][2]); MM(af[0][1],b1[0][1],acc[4][2]); \
  MM(af[0][0],b1[1][0],acc[4][3]); MM(af[0][1],b1[1][1],acc[4][3]); \
  MM(af[1][0],b1[0][0],acc[5][2]); MM(af[1][1],b1[0][1],acc[5][2]); \
  MM(af[1][0],b1[1][0],acc[5][3]); MM(af[1][1],b1[1][1],acc[5][3]); \
  MM(af[2][0],b1[0][0],acc[6][2]); MM(af[2][1],b1[0][1],acc[6][2]); \
  MM(af[2][0],b1[1][0],acc[6][3]); MM(af[2][1],b1[1][1],acc[6][3]); \
  MM(af[3][0],b1[0][0],acc[7][2]); MM(af[3][1],b1[0][1],acc[7][2]); \
  MM(af[3][0],b1[1][0],acc[7][3]); MM(af[3][1],b1[1][1],acc[7][3]); \
  __builtin_amdgcn_s_setprio(0); \
  BAR(); \
  STG(); \
  BAR(); \
  __builtin_amdgcn_s_setprio(1); \
  MM(af[0][0],b0[0][0],acc[4][0]); MM(af[0][1],b0[0][1],acc[4][0]); \
  MM(af[0][0],b0[1][0],acc[4][1]); MM(af[0][1],b0[1][1],acc[4][1]); \
  MM(af[1][0],b0[0][0],acc[5][0]); MM(af[1][1],b0[0][1],acc[5][0]); \
  MM(af[1][0],b0[1][0],acc[5][1]); MM(af[1][1],b0[1][1],acc[5][1]); \
  MM(af[2][0],b0[0][0],acc[6][0]); MM(af[2][1],b0[0][1],acc[6][0]); \
  MM(af[2][0],b0[1][0],acc[6][1]); MM(af[2][1],b0[1][1],acc[6][1]); \
  MM(af[3][0],b0[0][0],acc[7][0]); MM(af[3][1],b0[0][1],acc[7][0]); \
  MM(af[3][0],b0[1][0],acc[7][1]); MM(af[3][1],b0[1][1],acc[7][1]); \
  __builtin_amdgcn_s_setprio(0); \
  VMASM; \
  BAR(); \
} while (0)

template<int EPI>
__global__ __launch_bounds__(512, 2) void gemm8(
    const bf16u* __restrict__ Aall, const bf16u* __restrict__ Ball,
    int Kld, int Kloop, long splitOff, long sAz, long sBz,
    bf16u* __restrict__ D0, float scale)
{
    const int gx = gridDim.x, gy = gridDim.y;
    const int nwg = gx * gy * gridDim.z;
    int flat = blockIdx.x + gx * (blockIdx.y + gy * blockIdx.z);
    int swz = (nwg & 7) ? flat : (flat & 7) * (nwg >> 3) + (flat >> 3);
    const int bx = swz % gx;
    int tq = swz / gx;
    const int by = tq % gy;
    const int z = tq / gy;

    const int tid = threadIdx.x;
    const int l = tid & 63, w = tid >> 6;
    const int fr = l & 15, fq = l >> 4;
    const int wr = w >> 2, wc = w & 3;
    const bf16u* A = Aall + (long)(z & 7) * sAz + (long)(z >> 3) * splitOff;
    const bf16u* B = Ball + (long)(z & 7) * sBz + (long)(z >> 3) * splitOff;
    const int m0 = by << 8, n0 = bx << 8;

    __shared__ __align__(16) bf16u S[65536];   // 128 KB

    f32x4 acc[8][4];
#pragma unroll
    for (int i = 0; i < 8; ++i)
#pragma unroll
        for (int j = 0; j < 4; ++j) acc[i][j] = (f32x4){0.f, 0.f, 0.f, 0.f};

    const int NT = Kloop >> 6;
    const int nht = NT << 2;
    const int NI = NT >> 1;
    int q = 0;

    const long arow = (long)(m0 + w * 16 + fr) * Kld + fq * 8;
    const long brow = (long)(n0 + w * 16 + fr) * Kld + fq * 8;
    const long r128 = (long)128 * Kld;

    STG(); STG(); STG(); STG(); STG(); STG();
    asm volatile("s_waitcnt vmcnt(4)" ::: "memory");
    BAR();

    short8 af[4][2], b0[2][2], b1[2][2];

    for (int i = 0; i < NI - 1; ++i) {
        KTILE(2 * i,     asm volatile("s_waitcnt vmcnt(4)" ::: "memory"));
        KTILE(2 * i + 1, asm volatile("s_waitcnt vmcnt(4)" ::: "memory"));
    }
    KTILE(2 * NI - 2, asm volatile("s_waitcnt vmcnt(0)" ::: "memory"));
    KTILE(2 * NI - 1, (void)0);

    const int colb = n0 + wc * 64;
    const int rowb = m0 + wr * 128;
    if constexpr (EPI == 2) {
#pragma unroll
        for (int m = 0; m < 8; ++m)
#pragma unroll
            for (int n = 0; n < 4; ++n) {
                const int col = colb + n * 16 + fr;
                const int rb = rowb + m * 16 + fq * 4;
#pragma unroll
                for (int r = 0; r < 4; ++r)
                    D0[((long)z << 20) + ((long)(rb + r) << 10) + col] = f2bf(acc[m][n][r] * scale);
            }
    } else {  // EPI == 3
#pragma unroll
        for (int m = 0; m < 8; ++m)
#pragma unroll
            for (int n = 0; n < 4; ++n) {
                const int col = colb + n * 16 + fr;
                const int cb = col >> 6, d = col & 63;
                const int rb = rowb + m * 16 + fq * 4;
#pragma unroll
                for (int r = 0; r < 4; ++r)
                    D0[((long)(cb * 1024 + rb + r) << 9) + (z & 7) * 64 + d] = f2bf(acc[m][n][r]);
            }
    }
}

// x (fp32) -> bf16
__global__ __launch_bounds__(256) void cvt_x(const float* __restrict__ in,
                                             bf16u* __restrict__ out) {
    const long idx = (long)(blockIdx.x * 256 + threadIdx.x) * 4;
    const float4 v = *(const float4*)(in + idx);
    ushort4 o;
    o.x = f2bf(v.x); o.y = f2bf(v.y); o.z = f2bf(v.z); o.w = f2bf(v.w);
    *(ushort4*)(out + idx) = o;
}

// out[c*R + r] = bf16(in[r*C + c])
__global__ __launch_bounds__(256) void transpose_cvt(const float* __restrict__ in,
                                                     bf16u* __restrict__ out,
                                                     int R, int C) {
    const int idx = blockIdx.x * 256 + threadIdx.x;
    if (idx < R * C) {
        const int r = idx / C, c = idx % C;
        out[(long)c * R + r] = f2bf(in[idx]);
    }
}

// softmax over 1024 elements of (partial0 + partial1); one block per row
__global__ __launch_bounds__(256) void softmax_rows2(const bf16u* __restrict__ attP,
                                                     bf16u* __restrict__ att) {
    const long base = (long)blockIdx.x << 10;
    const int tid = threadIdx.x;
    const uint2 u0 = *(const uint2*)(attP + base + tid * 4);
    const uint2 u1 = *(const uint2*)(attP + 8388608 + base + tid * 4);
    const float v0 = bf2f(u0.x & 0xffffu) + bf2f(u1.x & 0xffffu);
    const float v1 = bf2f(u0.x >> 16)     + bf2f(u1.x >> 16);
    const float v2 = bf2f(u0.y & 0xffffu) + bf2f(u1.y & 0xffffu);
    const float v3 = bf2f(u0.y >> 16)     + bf2f(u1.y >> 16);
    float m = fmaxf(fmaxf(v0, v1), fmaxf(v2, v3));
#pragma unroll
    for (int o = 32; o; o >>= 1) m = fmaxf(m, __shfl_xor(m, o));
    __shared__ float red[8];
    if ((tid & 63) == 0) red[tid >> 6] = m;
    __syncthreads();
    m = fmaxf(fmaxf(red[0], red[1]), fmaxf(red[2], red[3]));
    const float e0 = __expf(v0 - m), e1 = __expf(v1 - m);
    const float e2 = __expf(v2 - m), e3 = __expf(v3 - m);
    float s = e0 + e1 + e2 + e3;
#pragma unroll
    for (int o = 32; o; o >>= 1) s += __shfl_xor(s, o);
    if ((tid & 63) == 0) red[4 + (tid >> 6)] = s;
    __syncthreads();
    const float inv = 1.0f / (red[4] + red[5] + red[6] + red[7]);
    uint2 o2;
    o2.x = (unsigned)f2bf(e0 * inv) | ((unsigned)f2bf(e1 * inv) << 16);
    o2.y = (unsigned)f2bf(e2 * inv) | ((unsigned)f2bf(e3 * inv) << 16);
    *(uint2*)(att + base + tid * 4) = o2;
}

extern "C" void kernel_launch(void* const* d_in, const int* in_sizes, int n_in,
                              void* d_out, int out_size, void* d_ws, size_t ws_size,
                              hipStream_t stream) {
    (void)in_sizes; (void)n_in; (void)out_size; (void)ws_size;
    const float* x    = (const float*)d_in[0];
    const float* Wq   = (const float*)d_in[1];
    const float* Wkv  = (const float*)d_in[2];
    const float* Wout = (const float*)d_in[3];
    const float* bout = (const float*)d_in[4];
    float* out = (float*)d_out;

    char* ws = (char*)d_ws;
    bf16u* xb    = (bf16u*)(ws);                    // 32768 x 256        16.0 MB
    bf16u* WqkvT = (bf16u*)(ws + 16777216);         // 1536 x 256          0.75 MB
    bf16u* WoutT = (bf16u*)(ws + 17563648);         // 256 x 512           0.25 MB
    bf16u* Qt    = (bf16u*)(ws + 17825792);         // 8 x 1024 x 2048    32 MB
    bf16u* Kt    = (bf16u*)(ws + 51380224);         // 8 x 1024 x 2048    32 MB
    bf16u* Vt2   = (bf16u*)(ws + 84934656);         // 8 x 2048 x 1024    32 MB
    bf16u* att   = (bf16u*)(ws + 118489088);        // 8 x 1024 x 1024    16 MB
    bf16u* out2  = (bf16u*)(ws + 135266304);        // 32768 x 512        32 MB
    // attP (split-K partial logits, 2 x 8 x 1024 x 1024 bf16 = 32 MB) reuses
    // the out2 region: written by stage 2, consumed by softmax BEFORE stage 3
    // overwrites the region with out2.
    bf16u* attP  = out2;

    cvt_x<<<8192, 256, 0, stream>>>(x, xb);
    transpose_cvt<<<512, 256, 0, stream>>>(Wq, WqkvT, 256, 512);
    transpose_cvt<<<1024, 256, 0, stream>>>(Wkv, WqkvT + 512 * 256, 256, 1024);
    transpose_cvt<<<512, 256, 0, stream>>>(Wout, WoutT, 512, 256);

    const float scale = 1.0f / (8.0f * sqrtf(32.0f));

    // stage 1: qkv = xb @ WqkvT^T (M=32768, N=1536, K=256) -> Qt/Kt/Vt2
    gemm_bt<1><<<dim3(12, 256, 1), 256, 0, stream>>>(
        xb, WqkvT, 256, 0, 0, Qt, Kt, Vt2, nullptr, nullptr, 0.f);

    // stage 2 (split-K=2): partial dots, z = half*8 + head -> attP
    gemm8<2><<<dim3(4, 4, 16), 512, 0, stream>>>(
        Qt, Kt, 2048, 1024, 1024, 1024L * 2048, 1024L * 2048, attP, scale);

    softmax_rows2<<<8192, 256, 0, stream>>>(attP, att);

    // stage 3: per head, out = att_h @ Vt2_h^T (M=1024, N=2048, K=1024) -> out2
    gemm8<3><<<dim3(8, 4, 8), 512, 0, stream>>>(
        att, Vt2, 1024, 1024, 0, 1024L * 1024, 2048L * 1024, out2, 0.f);

    // stage 4: final = out2 @ WoutT^T + bout (M=32768, N=256, K=512) -> fp32 out
    gemm_bt<4><<<dim3(2, 256, 1), 256, 0, stream>>>(
        out2, WoutT, 512, 0, 0, nullptr, nullptr, nullptr, out, bout, 0.f);
}

// Round 8
// 258.237 us; speedup vs baseline: 1.4029x; 1.0374x over previous
//
#include <hip/hip_runtime.h>
#include <math.h>

typedef unsigned short bf16u;
typedef __attribute__((ext_vector_type(8))) short short8;
typedef __attribute__((ext_vector_type(4))) float f32x4;

__device__ __forceinline__ bf16u f2bf(float f) {
    unsigned int u = __float_as_uint(f);
    u += 0x7fffu + ((u >> 16) & 1u);
    return (bf16u)(u >> 16);
}
__device__ __forceinline__ float bf2f(bf16u h) {
    return __uint_as_float(((unsigned int)h) << 16);
}

__device__ __forceinline__ void gload16(const void* g, void* s) {
    __builtin_amdgcn_global_load_lds((const __attribute__((address_space(1))) void*)g,
                                     (__attribute__((address_space(3))) void*)s, 16, 0, 0);
}

// ---------------------------------------------------------------------------
// 2-phase 128x128 bf16 GEMM (C = A @ B^T), 4 waves, double-buffered LDS,
// fragment-major (conflict-free). Epilogues stage the C-tile through LDS
// (pad-132 rows: bank = 2*rl + cl/2 -> 32 banks covered -> ~conflict-free)
// so ALL global writes are 16-byte coalesced stores (store-issue was the
// R7 bottleneck: 33.5M scalar 2B stores ~= 55us of pure issue).
// ---------------------------------------------------------------------------
template<int EPI>
__global__ __launch_bounds__(256, 4) void gemm_bt(
    const bf16u* __restrict__ Aall, const bf16u* __restrict__ Ball, int K,
    long strideAz, long strideBz,
    bf16u* __restrict__ D0, bf16u* __restrict__ D1, bf16u* __restrict__ D2,
    float* __restrict__ Df, const float* __restrict__ bias, float scale)
{
    // bijective XCD-chunked swizzle over the flattened grid
    const int gx = gridDim.x, gy = gridDim.y;
    const int nwg = gx * gy * gridDim.z;
    int flat = blockIdx.x + gx * (blockIdx.y + gy * blockIdx.z);
    int swz = (nwg & 7) ? flat : (flat & 7) * (nwg >> 3) + (flat >> 3);
    const int bx = swz % gx;
    const int t1 = swz / gx;
    const int by = t1 % gy;
    const int z  = t1 / gy;

    const int tid = threadIdx.x;
    const int l = tid & 63, w = tid >> 6;
    const int fr = l & 15, fq = l >> 4;
    const int kb = fq * 8;
    const bf16u* A = Aall + (long)z * strideAz;
    const bf16u* B = Ball + (long)z * strideBz;
    const int m0 = by * 128, n0 = bx * 128;

    __shared__ __align__(16) bf16u S[16896];   // 33792 B (128 x 132 staging)

    f32x4 acc[4][4];
#pragma unroll
    for (int i = 0; i < 4; ++i)
#pragma unroll
        for (int j = 0; j < 4; ++j) acc[i][j] = (f32x4){0.f, 0.f, 0.f, 0.f};

    const long aoff0 = (long)(m0 + w * 16 + fr) * K + kb;
    const long aoff1 = (long)(m0 + (w + 4) * 16 + fr) * K + kb;
    const long boff0 = (long)(n0 + w * 16 + fr) * K + kb;
    const long boff1 = (long)(n0 + (w + 4) * 16 + fr) * K + kb;

    const int wr = w >> 1, wc = w & 1;

#define STAGE(c, k0) do { \
        bf16u* as_ = S + (c) * 4096; \
        bf16u* bs_ = S + 8192 + (c) * 4096; \
        gload16(A + aoff0 + (k0), as_ + w * 512); \
        gload16(A + aoff1 + (k0), as_ + w * 512 + 2048); \
        gload16(B + boff0 + (k0), bs_ + w * 512); \
        gload16(B + boff1 + (k0), bs_ + w * 512 + 2048); \
    } while (0)

    STAGE(0, 0);
    __syncthreads();

    int cur = 0;
    for (int k0 = 0; k0 < K; k0 += 32) {
        if (k0 + 32 < K) STAGE(cur ^ 1, k0 + 32);

        const bf16u* Ac = S + cur * 4096;
        const bf16u* Bc = S + 8192 + cur * 4096;
        short8 af[4], bg[4];
#pragma unroll
        for (int t = 0; t < 4; ++t) {
            af[t] = *(const short8*)(Ac + (wr * 4 + t) * 512 + l * 8);
            bg[t] = *(const short8*)(Bc + (wc * 4 + t) * 512 + l * 8);
        }
#pragma unroll
        for (int mt = 0; mt < 4; ++mt)
#pragma unroll
            for (int nt = 0; nt < 4; ++nt)
                acc[mt][nt] = __builtin_amdgcn_mfma_f32_16x16x32_bf16(
                    af[mt], bg[nt], acc[mt][nt], 0, 0, 0);
        __syncthreads();
        cur ^= 1;
    }
#undef STAGE

    if constexpr (EPI == 1) {
        if (n0 >= 1024) {
            // ---- V blocks: transposed staging (pad 132), coalesced 16B out
#pragma unroll
            for (int mt = 0; mt < 4; ++mt) {
#pragma unroll
                for (int nt = 0; nt < 4; ++nt) {
                    const f32x4 v = acc[mt][nt];
                    const int cl = wc * 64 + nt * 16 + fr;
                    const int rl = wr * 64 + mt * 16 + fq * 4;
                    ushort4 pk;
                    pk.x = f2bf(v[0]); pk.y = f2bf(v[1]);
                    pk.z = f2bf(v[2]); pk.w = f2bf(v[3]);
                    *(ushort4*)(S + cl * 132 + rl) = pk;   // transposed store
                }
            }
            __syncthreads();
            const int c2 = n0 - 1024;
            const int rr = m0 >> 10, i0 = m0 & 1023;
            const int rowt = tid >> 4, c0 = (tid & 15) * 8;
#pragma unroll
            for (int p = 0; p < 8; ++p) {
                const int row = p * 16 + rowt;            // v-channel within tile
                const int col = c2 + row;
                const int h = col >> 6, d = col & 63;
                const ushort4 lo = *(const ushort4*)(S + row * 132 + c0);
                const ushort4 hi = *(const ushort4*)(S + row * 132 + c0 + 4);
                short8 v;
                v[0] = lo.x; v[1] = lo.y; v[2] = lo.z; v[3] = lo.w;
                v[4] = hi.x; v[5] = hi.y; v[6] = hi.z; v[7] = hi.w;
                *(short8*)(D2 + ((long)(h * 2048 + rr * 64 + d) << 10) + i0 + c0) = v;
            }
        } else {
            // ---- Q/K blocks: row-major staging (pad 132), coalesced 16B out
#pragma unroll
            for (int mt = 0; mt < 4; ++mt) {
#pragma unroll
                for (int nt = 0; nt < 4; ++nt) {
                    const int cl = wc * 64 + nt * 16 + fr;
                    const int rl = wr * 64 + mt * 16 + fq * 4;
#pragma unroll
                    for (int r = 0; r < 4; ++r)
                        S[(rl + r) * 132 + cl] = f2bf(acc[mt][nt][r]);
                }
            }
            __syncthreads();
            bf16u* Dqk = (n0 < 512) ? D0 : D1;
            const int hbase = ((n0 < 512) ? n0 : n0 - 512) >> 6;
            const int rr = m0 >> 10, i0 = m0 & 1023;
#pragma unroll
            for (int p = 0; p < 8; ++p) {
                const int idx = p * 256 + tid;
                const int lane8 = idx & 7;
                const int row_o = idx >> 3;          // 0..255 = hl*128 + il
                const int hl = row_o >> 7, il = row_o & 127;
                const int cbase = hl * 64 + lane8 * 8;
                const ushort4 lo = *(const ushort4*)(S + il * 132 + cbase);
                const ushort4 hi = *(const ushort4*)(S + il * 132 + cbase + 4);
                short8 v;
                v[0] = lo.x; v[1] = lo.y; v[2] = lo.z; v[3] = lo.w;
                v[4] = hi.x; v[5] = hi.y; v[6] = hi.z; v[7] = hi.w;
                *(short8*)(Dqk + (((long)((hbase + hl) * 1024 + i0 + il)) << 11)
                           + rr * 64 + lane8 * 8) = v;
            }
        }
    } else {
#pragma unroll
        for (int mt = 0; mt < 4; ++mt) {
#pragma unroll
            for (int nt = 0; nt < 4; ++nt) {
                const f32x4 v = acc[mt][nt];
                const int col = n0 + wc * 64 + nt * 16 + fr;
                const int rbase = m0 + wr * 64 + mt * 16 + fq * 4;
#pragma unroll
                for (int r = 0; r < 4; ++r)
                    Df[(long)(rbase + r) * 256 + col] = v[r] + bias[col];
            }
        }
    }
}

// ---------------------------------------------------------------------------
// 256x256 8-phase bf16 GEMM (C = A @ B^T), 8 waves (2M x 4N), BK=64.
// RAW s_barrier + counted vmcnt(4) checkpoints (verified R4 schedule).
// Kld = row stride; Kloop = contracted length; splitOff = per-(z>>3) K offset
// (split-K: z&7 selects head, z>>3 selects K-half). EPI=2: scaled bf16
// partial logits [z][i][j]; EPI=3: PV output scatter.
// ---------------------------------------------------------------------------
#define MM(a_, b_, c_) c_ = __builtin_amdgcn_mfma_f32_16x16x32_bf16(a_, b_, c_, 0, 0, 0)
#define BAR() __builtin_amdgcn_s_barrier()

#define STG() do { if (q < nht) { \
    const int t_ = q >> 2, p_ = q & 3; \
    const bf16u* P_ = (p_ < 2) ? B : A; \
    const long s_ = ((p_ < 2) ? brow : arow) + ((p_ & 1) ? r128 : 0) + t_ * 64; \
    bf16u* d_ = S + ((t_ & 1) << 15) + ((p_ < 2) ? 16384 : 0) + ((p_ & 1) << 12) + (w << 9); \
    gload16(P_ + s_, d_); \
    gload16(P_ + s_ + 32, d_ + 8192); \
  } ++q; } while (0)

#define RDA(dst, t, m, kk) dst = *(const short8*)(S + (((t) & 1) << 15) + ((kk) << 13) + ((wr * 8 + (m)) << 9) + (l << 3))
#define RDB(dst, t, n, kk) dst = *(const short8*)(S + (((t) & 1) << 15) + 16384 + ((kk) << 13) + ((wc * 4 + (n)) << 9) + (l << 3))

#define KTILE(t, VMASM) do { \
  RDA(af[0][0],t,0,0); RDA(af[0][1],t,0,1); RDA(af[1][0],t,1,0); RDA(af[1][1],t,1,1); \
  RDA(af[2][0],t,2,0); RDA(af[2][1],t,2,1); RDA(af[3][0],t,3,0); RDA(af[3][1],t,3,1); \
  RDB(b0[0][0],t,0,0); RDB(b0[0][1],t,0,1); RDB(b0[1][0],t,1,0); RDB(b0[1][1],t,1,1); \
  STG(); \
  BAR(); \
  __builtin_amdgcn_s_setprio(1); \
  MM(af[0][0],b0[0][0],acc[0][0]); MM(af[0][1],b0[0][1],acc[0][0]); \
  MM(af[0][0],b0[1][0],acc[0][1]); MM(af[0][1],b0[1][1],acc[0][1]); \
  MM(af[1][0],b0[0][0],acc[1][0]); MM(af[1][1],b0[0][1],acc[1][0]); \
  MM(af[1][0],b0[1][0],acc[1][1]); MM(af[1][1],b0[1][1],acc[1][1]); \
  MM(af[2][0],b0[0][0],acc[2][0]); MM(af[2][1],b0[0][1],acc[2][0]); \
  MM(af[2][0],b0[1][0],acc[2][1]); MM(af[2][1],b0[1][1],acc[2][1]); \
  MM(af[3][0],b0[0][0],acc[3][0]); MM(af[3][1],b0[0][1],acc[3][0]); \
  MM(af[3][0],b0[1][0],acc[3][1]); MM(af[3][1],b0[1][1],acc[3][1]); \
  __builtin_amdgcn_s_setprio(0); \
  BAR(); \
  RDB(b1[0][0],t,2,0); RDB(b1[0][1],t,2,1); RDB(b1[1][0],t,3,0); RDB(b1[1][1],t,3,1); \
  STG(); \
  BAR(); \
  __builtin_amdgcn_s_setprio(1); \
  MM(af[0][0],b1[0][0],acc[0][2]); MM(af[0][1],b1[0][1],acc[0][2]); \
  MM(af[0][0],b1[1][0],acc[0][3]); MM(af[0][1],b1[1][1],acc[0][3]); \
  MM(af[1][0],b1[0][0],acc[1][2]); MM(af[1][1],b1[0][1],acc[1][2]); \
  MM(af[1][0],b1[1][0],acc[1][3]); MM(af[1][1],b1[1][1],acc[1][3]); \
  MM(af[2][0],b1[0][0],acc[2][2]); MM(af[2][1],b1[0][1],acc[2][2]); \
  MM(af[2][0],b1[1][0],acc[2][3]); MM(af[2][1],b1[1][1],acc[2][3]); \
  MM(af[3][0],b1[0][0],acc[3][2]); MM(af[3][1],b1[0][1],acc[3][2]); \
  MM(af[3][0],b1[1][0],acc[3][3]); MM(af[3][1],b1[1][1],acc[3][3]); \
  __builtin_amdgcn_s_setprio(0); \
  BAR(); \
  RDA(af[0][0],t,4,0); RDA(af[0][1],t,4,1); RDA(af[1][0],t,5,0); RDA(af[1][1],t,5,1); \
  RDA(af[2][0],t,6,0); RDA(af[2][1],t,6,1); RDA(af[3][0],t,7,0); RDA(af[3][1],t,7,1); \
  STG(); \
  BAR(); \
  __builtin_amdgcn_s_setprio(1); \
  MM(af[0][0],b1[0][0],acc[4][2]); MM(af[0][1],b1[0][1],acc[4][2]); \
  MM(af[0][0],b1[1][0],acc[4][3]); MM(af[0][1],b1[1][1],acc[4][3]); \
  MM(af[1][0],b1[0][0],acc[5][2]); MM(af[1][1],b1[0][1],acc[5][2]); \
  MM(af[1][0],b1[1][0],acc[5][3]); MM(af[1][1],b1[1][1],acc[5][3]); \
  MM(af[2][0],b1[0][0],acc[6][2]); MM(af[2][1],b1[0][1],acc[6][2]); \
  MM(af[2][0],b1[1][0],acc[6][3]); MM(af[2][1],b1[1][1],acc[6][3]); \
  MM(af[3][0],b1[0][0],acc[7][2]); MM(af[3][1],b1[0][1],acc[7][2]); \
  MM(af[3][0],b1[1][0],acc[7][3]); MM(af[3][1],b1[1][1],acc[7][3]); \
  __builtin_amdgcn_s_setprio(0); \
  BAR(); \
  STG(); \
  BAR(); \
  __builtin_amdgcn_s_setprio(1); \
  MM(af[0][0],b0[0][0],acc[4][0]); MM(af[0][1],b0[0][1],acc[4][0]); \
  MM(af[0][0],b0[1][0],acc[4][1]); MM(af[0][1],b0[1][1],acc[4][1]); \
  MM(af[1][0],b0[0][0],acc[5][0]); MM(af[1][1],b0[0][1],acc[5][0]); \
  MM(af[1][0],b0[1][0],acc[5][1]); MM(af[1][1],b0[1][1],acc[5][1]); \
  MM(af[2][0],b0[0][0],acc[6][0]); MM(af[2][1],b0[0][1],acc[6][0]); \
  MM(af[2][0],b0[1][0],acc[6][1]); MM(af[2][1],b0[1][1],acc[6][1]); \
  MM(af[3][0],b0[0][0],acc[7][0]); MM(af[3][1],b0[0][1],acc[7][0]); \
  MM(af[3][0],b0[1][0],acc[7][1]); MM(af[3][1],b0[1][1],acc[7][1]); \
  __builtin_amdgcn_s_setprio(0); \
  VMASM; \
  BAR(); \
} while (0)

template<int EPI>
__global__ __launch_bounds__(512, 2) void gemm8(
    const bf16u* __restrict__ Aall, const bf16u* __restrict__ Ball,
    int Kld, int Kloop, long splitOff, long sAz, long sBz,
    bf16u* __restrict__ D0, float scale)
{
    const int gx = gridDim.x, gy = gridDim.y;
    const int nwg = gx * gy * gridDim.z;
    int flat = blockIdx.x + gx * (blockIdx.y + gy * blockIdx.z);
    int swz = (nwg & 7) ? flat : (flat & 7) * (nwg >> 3) + (flat >> 3);
    const int bx = swz % gx;
    int tq = swz / gx;
    const int by = tq % gy;
    const int z = tq / gy;

    const int tid = threadIdx.x;
    const int l = tid & 63, w = tid >> 6;
    const int fr = l & 15, fq = l >> 4;
    const int wr = w >> 2, wc = w & 3;
    const bf16u* A = Aall + (long)(z & 7) * sAz + (long)(z >> 3) * splitOff;
    const bf16u* B = Ball + (long)(z & 7) * sBz + (long)(z >> 3) * splitOff;
    const int m0 = by << 8, n0 = bx << 8;

    __shared__ __align__(16) bf16u S[65536];   // 128 KB

    f32x4 acc[8][4];
#pragma unroll
    for (int i = 0; i < 8; ++i)
#pragma unroll
        for (int j = 0; j < 4; ++j) acc[i][j] = (f32x4){0.f, 0.f, 0.f, 0.f};

    const int NT = Kloop >> 6;
    const int nht = NT << 2;
    const int NI = NT >> 1;
    int q = 0;

    const long arow = (long)(m0 + w * 16 + fr) * Kld + fq * 8;
    const long brow = (long)(n0 + w * 16 + fr) * Kld + fq * 8;
    const long r128 = (long)128 * Kld;

    STG(); STG(); STG(); STG(); STG(); STG();
    asm volatile("s_waitcnt vmcnt(4)" ::: "memory");
    BAR();

    short8 af[4][2], b0[2][2], b1[2][2];

    for (int i = 0; i < NI - 1; ++i) {
        KTILE(2 * i,     asm volatile("s_waitcnt vmcnt(4)" ::: "memory"));
        KTILE(2 * i + 1, asm volatile("s_waitcnt vmcnt(4)" ::: "memory"));
    }
    KTILE(2 * NI - 2, asm volatile("s_waitcnt vmcnt(0)" ::: "memory"));
    KTILE(2 * NI - 1, (void)0);

    const int colb = n0 + wc * 64;
    const int rowb = m0 + wr * 128;
    if constexpr (EPI == 2) {
#pragma unroll
        for (int m = 0; m < 8; ++m)
#pragma unroll
            for (int n = 0; n < 4; ++n) {
                const int col = colb + n * 16 + fr;
                const int rb = rowb + m * 16 + fq * 4;
#pragma unroll
                for (int r = 0; r < 4; ++r)
                    D0[((long)z << 20) + ((long)(rb + r) << 10) + col] = f2bf(acc[m][n][r] * scale);
            }
    } else {  // EPI == 3
#pragma unroll
        for (int m = 0; m < 8; ++m)
#pragma unroll
            for (int n = 0; n < 4; ++n) {
                const int col = colb + n * 16 + fr;
                const int cb = col >> 6, d = col & 63;
                const int rb = rowb + m * 16 + fq * 4;
#pragma unroll
                for (int r = 0; r < 4; ++r)
                    D0[((long)(cb * 1024 + rb + r) << 9) + (z & 7) * 64 + d] = f2bf(acc[m][n][r]);
            }
    }
}

// x (fp32) -> bf16
__global__ __launch_bounds__(256) void cvt_x(const float* __restrict__ in,
                                             bf16u* __restrict__ out) {
    const long idx = (long)(blockIdx.x * 256 + threadIdx.x) * 4;
    const float4 v = *(const float4*)(in + idx);
    ushort4 o;
    o.x = f2bf(v.x); o.y = f2bf(v.y); o.z = f2bf(v.z); o.w = f2bf(v.w);
    *(ushort4*)(out + idx) = o;
}

// out[c*R + r] = bf16(in[r*C + c])
__global__ __launch_bounds__(256) void transpose_cvt(const float* __restrict__ in,
                                                     bf16u* __restrict__ out,
                                                     int R, int C) {
    const int idx = blockIdx.x * 256 + threadIdx.x;
    if (idx < R * C) {
        const int r = idx / C, c = idx % C;
        out[(long)c * R + r] = f2bf(in[idx]);
    }
}

// softmax over 1024 elements of (partial0 + partial1); one block per row
__global__ __launch_bounds__(256) void softmax_rows2(const bf16u* __restrict__ attP,
                                                     bf16u* __restrict__ att) {
    const long base = (long)blockIdx.x << 10;
    const int tid = threadIdx.x;
    const uint2 u0 = *(const uint2*)(attP + base + tid * 4);
    const uint2 u1 = *(const uint2*)(attP + 8388608 + base + tid * 4);
    const float v0 = bf2f(u0.x & 0xffffu) + bf2f(u1.x & 0xffffu);
    const float v1 = bf2f(u0.x >> 16)     + bf2f(u1.x >> 16);
    const float v2 = bf2f(u0.y & 0xffffu) + bf2f(u1.y & 0xffffu);
    const float v3 = bf2f(u0.y >> 16)     + bf2f(u1.y >> 16);
    float m = fmaxf(fmaxf(v0, v1), fmaxf(v2, v3));
#pragma unroll
    for (int o = 32; o; o >>= 1) m = fmaxf(m, __shfl_xor(m, o));
    __shared__ float red[8];
    if ((tid & 63) == 0) red[tid >> 6] = m;
    __syncthreads();
    m = fmaxf(fmaxf(red[0], red[1]), fmaxf(red[2], red[3]));
    const float e0 = __expf(v0 - m), e1 = __expf(v1 - m);
    const float e2 = __expf(v2 - m), e3 = __expf(v3 - m);
    float s = e0 + e1 + e2 + e3;
#pragma unroll
    for (int o = 32; o; o >>= 1) s += __shfl_xor(s, o);
    if ((tid & 63) == 0) red[4 + (tid >> 6)] = s;
    __syncthreads();
    const float inv = 1.0f / (red[4] + red[5] + red[6] + red[7]);
    uint2 o2;
    o2.x = (unsigned)f2bf(e0 * inv) | ((unsigned)f2bf(e1 * inv) << 16);
    o2.y = (unsigned)f2bf(e2 * inv) | ((unsigned)f2bf(e3 * inv) << 16);
    *(uint2*)(att + base + tid * 4) = o2;
}

extern "C" void kernel_launch(void* const* d_in, const int* in_sizes, int n_in,
                              void* d_out, int out_size, void* d_ws, size_t ws_size,
                              hipStream_t stream) {
    (void)in_sizes; (void)n_in; (void)out_size; (void)ws_size;
    const float* x    = (const float*)d_in[0];
    const float* Wq   = (const float*)d_in[1];
    const float* Wkv  = (const float*)d_in[2];
    const float* Wout = (const float*)d_in[3];
    const float* bout = (const float*)d_in[4];
    float* out = (float*)d_out;

    char* ws = (char*)d_ws;
    bf16u* xb    = (bf16u*)(ws);                    // 32768 x 256        16.0 MB
    bf16u* WqkvT = (bf16u*)(ws + 16777216);         // 1536 x 256          0.75 MB
    bf16u* WoutT = (bf16u*)(ws + 17563648);         // 256 x 512           0.25 MB
    bf16u* Qt    = (bf16u*)(ws + 17825792);         // 8 x 1024 x 2048    32 MB
    bf16u* Kt    = (bf16u*)(ws + 51380224);         // 8 x 1024 x 2048    32 MB
    bf16u* Vt2   = (bf16u*)(ws + 84934656);         // 8 x 2048 x 1024    32 MB
    bf16u* att   = (bf16u*)(ws + 118489088);        // 8 x 1024 x 1024    16 MB
    bf16u* out2  = (bf16u*)(ws + 135266304);        // 32768 x 512        32 MB
    // attP (split-K partial logits, 2 x 8 x 1024 x 1024 bf16 = 32 MB) reuses
    // the out2 region: written by stage 2, consumed by softmax BEFORE stage 3
    // overwrites the region with out2.
    bf16u* attP  = out2;

    cvt_x<<<8192, 256, 0, stream>>>(x, xb);
    transpose_cvt<<<512, 256, 0, stream>>>(Wq, WqkvT, 256, 512);
    transpose_cvt<<<1024, 256, 0, stream>>>(Wkv, WqkvT + 512 * 256, 256, 1024);
    transpose_cvt<<<512, 256, 0, stream>>>(Wout, WoutT, 512, 256);

    const float scale = 1.0f / (8.0f * sqrtf(32.0f));

    // stage 1: qkv = xb @ WqkvT^T (M=32768, N=1536, K=256) -> Qt/Kt/Vt2
    gemm_bt<1><<<dim3(12, 256, 1), 256, 0, stream>>>(
        xb, WqkvT, 256, 0, 0, Qt, Kt, Vt2, nullptr, nullptr, 0.f);

    // stage 2 (split-K=2): partial dots, z = half*8 + head -> attP
    gemm8<2><<<dim3(4, 4, 16), 512, 0, stream>>>(
        Qt, Kt, 2048, 1024, 1024, 1024L * 2048, 1024L * 2048, attP, scale);

    softmax_rows2<<<8192, 256, 0, stream>>>(attP, att);

    // stage 3: per head, out = att_h @ Vt2_h^T (M=1024, N=2048, K=1024) -> out2
    gemm8<3><<<dim3(8, 4, 8), 512, 0, stream>>>(
        att, Vt2, 1024, 1024, 0, 1024L * 1024, 2048L * 1024, out2, 0.f);

    // stage 4: final = out2 @ WoutT^T + bout (M=32768, N=256, K=512) -> fp32 out
    gemm_bt<4><<<dim3(2, 256, 1), 256, 0, stream>>>(
        out2, WoutT, 512, 0, 0, nullptr, nullptr, nullptr, out, bout, 0.f);
}

// Round 9
// 255.253 us; speedup vs baseline: 1.4193x; 1.0117x over previous
//
#include <hip/hip_runtime.h>
#include <math.h>

typedef unsigned short bf16u;
typedef __attribute__((ext_vector_type(8))) short short8;
typedef __attribute__((ext_vector_type(4))) float f32x4;

__device__ __forceinline__ bf16u f2bf(float f) {
    unsigned int u = __float_as_uint(f);
    u += 0x7fffu + ((u >> 16) & 1u);
    return (bf16u)(u >> 16);
}
__device__ __forceinline__ float bf2f(bf16u h) {
    return __uint_as_float(((unsigned int)h) << 16);
}

__device__ __forceinline__ void gload16(const void* g, void* s) {
    __builtin_amdgcn_global_load_lds((const __attribute__((address_space(1))) void*)g,
                                     (__attribute__((address_space(3))) void*)s, 16, 0, 0);
}

// ---------------------------------------------------------------------------
// 256x256 8-phase bf16 GEMM (C = A @ B^T), 8 waves (2M x 4N), BK=64.
// RAW s_barrier + counted vmcnt(4) checkpoints (verified R4/R7/R8 schedule).
// EPI=1: stage-1 QKV epilogue -> Qt/Kt/Vt2, LDS-staged (two half-tile passes,
//        pad-264 rows) so all global writes are coalesced 16B stores.
// EPI=2: scaled bf16 partial logits. EPI=3: PV output scatter.
// ---------------------------------------------------------------------------
#define MM(a_, b_, c_) c_ = __builtin_amdgcn_mfma_f32_16x16x32_bf16(a_, b_, c_, 0, 0, 0)
#define BAR() __builtin_amdgcn_s_barrier()

#define STG() do { if (q < nht) { \
    const int t_ = q >> 2, p_ = q & 3; \
    const bf16u* P_ = (p_ < 2) ? B : A; \
    const long s_ = ((p_ < 2) ? brow : arow) + ((p_ & 1) ? r128 : 0) + t_ * 64; \
    bf16u* d_ = S + ((t_ & 1) << 15) + ((p_ < 2) ? 16384 : 0) + ((p_ & 1) << 12) + (w << 9); \
    gload16(P_ + s_, d_); \
    gload16(P_ + s_ + 32, d_ + 8192); \
  } ++q; } while (0)

#define RDA(dst, t, m, kk) dst = *(const short8*)(S + (((t) & 1) << 15) + ((kk) << 13) + ((wr * 8 + (m)) << 9) + (l << 3))
#define RDB(dst, t, n, kk) dst = *(const short8*)(S + (((t) & 1) << 15) + 16384 + ((kk) << 13) + ((wc * 4 + (n)) << 9) + (l << 3))

#define KTILE(t, VMASM) do { \
  RDA(af[0][0],t,0,0); RDA(af[0][1],t,0,1); RDA(af[1][0],t,1,0); RDA(af[1][1],t,1,1); \
  RDA(af[2][0],t,2,0); RDA(af[2][1],t,2,1); RDA(af[3][0],t,3,0); RDA(af[3][1],t,3,1); \
  RDB(b0[0][0],t,0,0); RDB(b0[0][1],t,0,1); RDB(b0[1][0],t,1,0); RDB(b0[1][1],t,1,1); \
  STG(); \
  BAR(); \
  __builtin_amdgcn_s_setprio(1); \
  MM(af[0][0],b0[0][0],acc[0][0]); MM(af[0][1],b0[0][1],acc[0][0]); \
  MM(af[0][0],b0[1][0],acc[0][1]); MM(af[0][1],b0[1][1],acc[0][1]); \
  MM(af[1][0],b0[0][0],acc[1][0]); MM(af[1][1],b0[0][1],acc[1][0]); \
  MM(af[1][0],b0[1][0],acc[1][1]); MM(af[1][1],b0[1][1],acc[1][1]); \
  MM(af[2][0],b0[0][0],acc[2][0]); MM(af[2][1],b0[0][1],acc[2][0]); \
  MM(af[2][0],b0[1][0],acc[2][1]); MM(af[2][1],b0[1][1],acc[2][1]); \
  MM(af[3][0],b0[0][0],acc[3][0]); MM(af[3][1],b0[0][1],acc[3][0]); \
  MM(af[3][0],b0[1][0],acc[3][1]); MM(af[3][1],b0[1][1],acc[3][1]); \
  __builtin_amdgcn_s_setprio(0); \
  BAR(); \
  RDB(b1[0][0],t,2,0); RDB(b1[0][1],t,2,1); RDB(b1[1][0],t,3,0); RDB(b1[1][1],t,3,1); \
  STG(); \
  BAR(); \
  __builtin_amdgcn_s_setprio(1); \
  MM(af[0][0],b1[0][0],acc[0][2]); MM(af[0][1],b1[0][1],acc[0][2]); \
  MM(af[0][0],b1[1][0],acc[0][3]); MM(af[0][1],b1[1][1],acc[0][3]); \
  MM(af[1][0],b1[0][0],acc[1][2]); MM(af[1][1],b1[0][1],acc[1][2]); \
  MM(af[1][0],b1[1][0],acc[1][3]); MM(af[1][1],b1[1][1],acc[1][3]); \
  MM(af[2][0],b1[0][0],acc[2][2]); MM(af[2][1],b1[0][1],acc[2][2]); \
  MM(af[2][0],b1[1][0],acc[2][3]); MM(af[2][1],b1[1][1],acc[2][3]); \
  MM(af[3][0],b1[0][0],acc[3][2]); MM(af[3][1],b1[0][1],acc[3][2]); \
  MM(af[3][0],b1[1][0],acc[3][3]); MM(af[3][1],b1[1][1],acc[3][3]); \
  __builtin_amdgcn_s_setprio(0); \
  BAR(); \
  RDA(af[0][0],t,4,0); RDA(af[0][1],t,4,1); RDA(af[1][0],t,5,0); RDA(af[1][1],t,5,1); \
  RDA(af[2][0],t,6,0); RDA(af[2][1],t,6,1); RDA(af[3][0],t,7,0); RDA(af[3][1],t,7,1); \
  STG(); \
  BAR(); \
  __builtin_amdgcn_s_setprio(1); \
  MM(af[0][0],b1[0][0],acc[4][2]); MM(af[0][1],b1[0][1],acc[4][2]); \
  MM(af[0][0],b1[1][0],acc[4][3]); MM(af[0][1],b1[1][1],acc[4][3]); \
  MM(af[1][0],b1[0][0],acc[5][2]); MM(af[1][1],b1[0][1],acc[5][2]); \
  MM(af[1][0],b1[1][0],acc[5][3]); MM(af[1][1],b1[1][1],acc[5][3]); \
  MM(af[2][0],b1[0][0],acc[6][2]); MM(af[2][1],b1[0][1],acc[6][2]); \
  MM(af[2][0],b1[1][0],acc[6][3]); MM(af[2][1],b1[1][1],acc[6][3]); \
  MM(af[3][0],b1[0][0],acc[7][2]); MM(af[3][1],b1[0][1],acc[7][2]); \
  MM(af[3][0],b1[1][0],acc[7][3]); MM(af[3][1],b1[1][1],acc[7][3]); \
  __builtin_amdgcn_s_setprio(0); \
  BAR(); \
  STG(); \
  BAR(); \
  __builtin_amdgcn_s_setprio(1); \
  MM(af[0][0],b0[0][0],acc[4][0]); MM(af[0][1],b0[0][1],acc[4][0]); \
  MM(af[0][0],b0[1][0],acc[4][1]); MM(af[0][1],b0[1][1],acc[4][1]); \
  MM(af[1][0],b0[0][0],acc[5][0]); MM(af[1][1],b0[0][1],acc[5][0]); \
  MM(af[1][0],b0[1][0],acc[5][1]); MM(af[1][1],b0[1][1],acc[5][1]); \
  MM(af[2][0],b0[0][0],acc[6][0]); MM(af[2][1],b0[0][1],acc[6][0]); \
  MM(af[2][0],b0[1][0],acc[6][1]); MM(af[2][1],b0[1][1],acc[6][1]); \
  MM(af[3][0],b0[0][0],acc[7][0]); MM(af[3][1],b0[0][1],acc[7][0]); \
  MM(af[3][0],b0[1][0],acc[7][1]); MM(af[3][1],b0[1][1],acc[7][1]); \
  __builtin_amdgcn_s_setprio(0); \
  VMASM; \
  BAR(); \
} while (0)

template<int EPI>
__global__ __launch_bounds__(512, 2) void gemm8(
    const bf16u* __restrict__ Aall, const bf16u* __restrict__ Ball,
    int Kld, int Kloop, long splitOff, long sAz, long sBz,
    bf16u* __restrict__ D0, bf16u* __restrict__ D1, bf16u* __restrict__ D2,
    float scale)
{
    const int gx = gridDim.x, gy = gridDim.y;
    const int nwg = gx * gy * gridDim.z;
    int flat = blockIdx.x + gx * (blockIdx.y + gy * blockIdx.z);
    int swz = (nwg & 7) ? flat : (flat & 7) * (nwg >> 3) + (flat >> 3);
    const int bx = swz % gx;
    int tq = swz / gx;
    const int by = tq % gy;
    const int z = tq / gy;

    const int tid = threadIdx.x;
    const int l = tid & 63, w = tid >> 6;
    const int fr = l & 15, fq = l >> 4;
    const int wr = w >> 2, wc = w & 3;
    const bf16u* A = Aall + (long)(z & 7) * sAz + (long)(z >> 3) * splitOff;
    const bf16u* B = Ball + (long)(z & 7) * sBz + (long)(z >> 3) * splitOff;
    const int m0 = by << 8, n0 = bx << 8;

    __shared__ __align__(16) bf16u S[65536];   // 128 KB

    f32x4 acc[8][4];
#pragma unroll
    for (int i = 0; i < 8; ++i)
#pragma unroll
        for (int j = 0; j < 4; ++j) acc[i][j] = (f32x4){0.f, 0.f, 0.f, 0.f};

    const int NT = Kloop >> 6;
    const int nht = NT << 2;
    const int NI = NT >> 1;
    int q = 0;

    const long arow = (long)(m0 + w * 16 + fr) * Kld + fq * 8;
    const long brow = (long)(n0 + w * 16 + fr) * Kld + fq * 8;
    const long r128 = (long)128 * Kld;

    STG(); STG(); STG(); STG(); STG(); STG();
    asm volatile("s_waitcnt vmcnt(4)" ::: "memory");
    BAR();

    short8 af[4][2], b0[2][2], b1[2][2];

    for (int i = 0; i < NI - 1; ++i) {
        KTILE(2 * i,     asm volatile("s_waitcnt vmcnt(4)" ::: "memory"));
        KTILE(2 * i + 1, asm volatile("s_waitcnt vmcnt(4)" ::: "memory"));
    }
    KTILE(2 * NI - 2, asm volatile("s_waitcnt vmcnt(0)" ::: "memory"));
    KTILE(2 * NI - 1, (void)0);

    const int colb = n0 + wc * 64;
    const int rowb = m0 + wr * 128;
    if constexpr (EPI == 1) {
        const int rr = m0 >> 10, i0 = m0 & 1023;
        if (n0 >= 1024) {
            // ---- V tiles: transposed staging (pad 264), 2 passes over cols
            const int c2 = n0 - 1024;
#pragma unroll
            for (int pv = 0; pv < 2; ++pv) {
                __syncthreads();
                if ((wc >> 1) == pv) {
#pragma unroll
                    for (int m = 0; m < 8; ++m)
#pragma unroll
                        for (int n = 0; n < 4; ++n) {
                            const int cl = (wc & 1) * 64 + n * 16 + fr;   // 0..127
                            const int rowl = wr * 128 + m * 16 + fq * 4;  // 0..255
                            ushort4 pk;
                            pk.x = f2bf(acc[m][n][0]); pk.y = f2bf(acc[m][n][1]);
                            pk.z = f2bf(acc[m][n][2]); pk.w = f2bf(acc[m][n][3]);
                            *(ushort4*)(S + cl * 264 + rowl) = pk;
                        }
                }
                __syncthreads();
#pragma unroll
                for (int p = 0; p < 8; ++p) {
                    const int idx = p * 512 + tid;
                    const int ch = idx >> 5;          // v-channel 0..127
                    const int c8 = (idx & 31) * 8;    // i-offset
                    const int col = c2 + pv * 128 + ch;
                    const int h = col >> 6, d = col & 63;
                    *(short8*)(D2 + ((long)(h * 2048 + rr * 64 + d) << 10) + i0 + c8)
                        = *(const short8*)(S + ch * 264 + c8);
                }
            }
        } else {
            // ---- Q/K tiles: row-major staging (pad 264), 2 passes over rows
            bf16u* Dqk = (n0 < 512) ? D0 : D1;
            const int nq = (n0 < 512) ? n0 : n0 - 512;
#pragma unroll
            for (int p2 = 0; p2 < 2; ++p2) {
                __syncthreads();
                if (wr == p2) {
#pragma unroll
                    for (int m = 0; m < 8; ++m)
#pragma unroll
                        for (int n = 0; n < 4; ++n) {
                            const int cl = wc * 64 + n * 16 + fr;   // 0..255
                            const int rl = m * 16 + fq * 4;          // 0..127
#pragma unroll
                            for (int r = 0; r < 4; ++r)
                                S[(rl + r) * 264 + cl] = f2bf(acc[m][n][r]);
                        }
                }
                __syncthreads();
#pragma unroll
                for (int p = 0; p < 8; ++p) {
                    const int idx = p * 512 + tid;
                    const int row = idx >> 5;         // 0..127
                    const int col = (idx & 31) * 8;   // 0..248
                    const int h = (nq + col) >> 6, d0 = (nq + col) & 63;
                    const int il = p2 * 128 + row;
                    *(short8*)(Dqk + ((long)(h * 1024 + i0 + il) << 11) + rr * 64 + d0)
                        = *(const short8*)(S + row * 264 + col);
                }
            }
        }
    } else if constexpr (EPI == 2) {
#pragma unroll
        for (int m = 0; m < 8; ++m)
#pragma unroll
            for (int n = 0; n < 4; ++n) {
                const int col = colb + n * 16 + fr;
                const int rb = rowb + m * 16 + fq * 4;
#pragma unroll
                for (int r = 0; r < 4; ++r)
                    D0[((long)z << 20) + ((long)(rb + r) << 10) + col] = f2bf(acc[m][n][r] * scale);
            }
    } else {  // EPI == 3
#pragma unroll
        for (int m = 0; m < 8; ++m)
#pragma unroll
            for (int n = 0; n < 4; ++n) {
                const int col = colb + n * 16 + fr;
                const int cb = col >> 6, d = col & 63;
                const int rb = rowb + m * 16 + fq * 4;
#pragma unroll
                for (int r = 0; r < 4; ++r)
                    D0[((long)(cb * 1024 + rb + r) << 9) + (z & 7) * 64 + d] = f2bf(acc[m][n][r]);
            }
    }
}

// ---------------------------------------------------------------------------
// 2-phase 128x128 bf16 GEMM for stage 4 (C = A @ B^T + bias, fp32 out).
// Epilogue stages f32 tile halves through LDS (pad-132) -> float4 stores.
// ---------------------------------------------------------------------------
__global__ __launch_bounds__(256, 4) void gemm_out(
    const bf16u* __restrict__ A, const bf16u* __restrict__ B, int K,
    float* __restrict__ Df, const float* __restrict__ bias)
{
    const int gx = gridDim.x, gy = gridDim.y;
    const int nwg = gx * gy;
    int flat = blockIdx.x + gx * blockIdx.y;
    int swz = (nwg & 7) ? flat : (flat & 7) * (nwg >> 3) + (flat >> 3);
    const int bx = swz % gx, by = swz / gx;

    const int tid = threadIdx.x;
    const int l = tid & 63, w = tid >> 6;
    const int fr = l & 15, fq = l >> 4;
    const int kb = fq * 8;
    const int m0 = by * 128, n0 = bx * 128;

    __shared__ __align__(16) bf16u S[16896];   // 33792 B

    f32x4 acc[4][4];
#pragma unroll
    for (int i = 0; i < 4; ++i)
#pragma unroll
        for (int j = 0; j < 4; ++j) acc[i][j] = (f32x4){0.f, 0.f, 0.f, 0.f};

    const long aoff0 = (long)(m0 + w * 16 + fr) * K + kb;
    const long aoff1 = (long)(m0 + (w + 4) * 16 + fr) * K + kb;
    const long boff0 = (long)(n0 + w * 16 + fr) * K + kb;
    const long boff1 = (long)(n0 + (w + 4) * 16 + fr) * K + kb;

    const int wr = w >> 1, wc = w & 1;

#define STAGE(c, k0) do { \
        bf16u* as_ = S + (c) * 4096; \
        bf16u* bs_ = S + 8192 + (c) * 4096; \
        gload16(A + aoff0 + (k0), as_ + w * 512); \
        gload16(A + aoff1 + (k0), as_ + w * 512 + 2048); \
        gload16(B + boff0 + (k0), bs_ + w * 512); \
        gload16(B + boff1 + (k0), bs_ + w * 512 + 2048); \
    } while (0)

    STAGE(0, 0);
    __syncthreads();

    int cur = 0;
    for (int k0 = 0; k0 < K; k0 += 32) {
        if (k0 + 32 < K) STAGE(cur ^ 1, k0 + 32);

        const bf16u* Ac = S + cur * 4096;
        const bf16u* Bc = S + 8192 + cur * 4096;
        short8 af[4], bg[4];
#pragma unroll
        for (int t = 0; t < 4; ++t) {
            af[t] = *(const short8*)(Ac + (wr * 4 + t) * 512 + l * 8);
            bg[t] = *(const short8*)(Bc + (wc * 4 + t) * 512 + l * 8);
        }
#pragma unroll
        for (int mt = 0; mt < 4; ++mt)
#pragma unroll
            for (int nt = 0; nt < 4; ++nt)
                acc[mt][nt] = __builtin_amdgcn_mfma_f32_16x16x32_bf16(
                    af[mt], bg[nt], acc[mt][nt], 0, 0, 0);
        __syncthreads();
        cur ^= 1;
    }
#undef STAGE

    float* Sf = (float*)S;
#pragma unroll
    for (int p2 = 0; p2 < 2; ++p2) {
        __syncthreads();
        if (wr == p2) {
#pragma unroll
            for (int mt = 0; mt < 4; ++mt)
#pragma unroll
                for (int nt = 0; nt < 4; ++nt) {
                    const int cl = wc * 64 + nt * 16 + fr;
                    const float b = bias[n0 + cl];
                    const int rl = mt * 16 + fq * 4;   // 0..63
#pragma unroll
                    for (int r = 0; r < 4; ++r)
                        Sf[(rl + r) * 132 + cl] = acc[mt][nt][r] + b;
                }
        }
        __syncthreads();
#pragma unroll
        for (int p = 0; p < 8; ++p) {
            const int idx = p * 256 + tid;
            const int row = idx >> 5;           // 0..63
            const int c4 = (idx & 31) * 4;      // 0..124
            const float4 v = *(const float4*)(Sf + row * 132 + c4);
            *(float4*)(Df + (long)(m0 + p2 * 64 + row) * 256 + n0 + c4) = v;
        }
    }
}

// x (fp32) -> bf16
__global__ __launch_bounds__(256) void cvt_x(const float* __restrict__ in,
                                             bf16u* __restrict__ out) {
    const long idx = (long)(blockIdx.x * 256 + threadIdx.x) * 4;
    const float4 v = *(const float4*)(in + idx);
    ushort4 o;
    o.x = f2bf(v.x); o.y = f2bf(v.y); o.z = f2bf(v.z); o.w = f2bf(v.w);
    *(ushort4*)(out + idx) = o;
}

// out[c*R + r] = bf16(in[r*C + c])
__global__ __launch_bounds__(256) void transpose_cvt(const float* __restrict__ in,
                                                     bf16u* __restrict__ out,
                                                     int R, int C) {
    const int idx = blockIdx.x * 256 + threadIdx.x;
    if (idx < R * C) {
        const int r = idx / C, c = idx % C;
        out[(long)c * R + r] = f2bf(in[idx]);
    }
}

// softmax over 1024 elements of (partial0 + partial1); one block per row
__global__ __launch_bounds__(256) void softmax_rows2(const bf16u* __restrict__ attP,
                                                     bf16u* __restrict__ att) {
    const long base = (long)blockIdx.x << 10;
    const int tid = threadIdx.x;
    const uint2 u0 = *(const uint2*)(attP + base + tid * 4);
    const uint2 u1 = *(const uint2*)(attP + 8388608 + base + tid * 4);
    const float v0 = bf2f(u0.x & 0xffffu) + bf2f(u1.x & 0xffffu);
    const float v1 = bf2f(u0.x >> 16)     + bf2f(u1.x >> 16);
    const float v2 = bf2f(u0.y & 0xffffu) + bf2f(u1.y & 0xffffu);
    const float v3 = bf2f(u0.y >> 16)     + bf2f(u1.y >> 16);
    float m = fmaxf(fmaxf(v0, v1), fmaxf(v2, v3));
#pragma unroll
    for (int o = 32; o; o >>= 1) m = fmaxf(m, __shfl_xor(m, o));
    __shared__ float red[8];
    if ((tid & 63) == 0) red[tid >> 6] = m;
    __syncthreads();
    m = fmaxf(fmaxf(red[0], red[1]), fmaxf(red[2], red[3]));
    const float e0 = __expf(v0 - m), e1 = __expf(v1 - m);
    const float e2 = __expf(v2 - m), e3 = __expf(v3 - m);
    float s = e0 + e1 + e2 + e3;
#pragma unroll
    for (int o = 32; o; o >>= 1) s += __shfl_xor(s, o);
    if ((tid & 63) == 0) red[4 + (tid >> 6)] = s;
    __syncthreads();
    const float inv = 1.0f / (red[4] + red[5] + red[6] + red[7]);
    uint2 o2;
    o2.x = (unsigned)f2bf(e0 * inv) | ((unsigned)f2bf(e1 * inv) << 16);
    o2.y = (unsigned)f2bf(e2 * inv) | ((unsigned)f2bf(e3 * inv) << 16);
    *(uint2*)(att + base + tid * 4) = o2;
}

extern "C" void kernel_launch(void* const* d_in, const int* in_sizes, int n_in,
                              void* d_out, int out_size, void* d_ws, size_t ws_size,
                              hipStream_t stream) {
    (void)in_sizes; (void)n_in; (void)out_size; (void)ws_size;
    const float* x    = (const float*)d_in[0];
    const float* Wq   = (const float*)d_in[1];
    const float* Wkv  = (const float*)d_in[2];
    const float* Wout = (const float*)d_in[3];
    const float* bout = (const float*)d_in[4];
    float* out = (float*)d_out;

    char* ws = (char*)d_ws;
    bf16u* xb    = (bf16u*)(ws);                    // 32768 x 256        16.0 MB
    bf16u* WqkvT = (bf16u*)(ws + 16777216);         // 1536 x 256          0.75 MB
    bf16u* WoutT = (bf16u*)(ws + 17563648);         // 256 x 512           0.25 MB
    bf16u* Qt    = (bf16u*)(ws + 17825792);         // 8 x 1024 x 2048    32 MB
    bf16u* Kt    = (bf16u*)(ws + 51380224);         // 8 x 1024 x 2048    32 MB
    bf16u* Vt2   = (bf16u*)(ws + 84934656);         // 8 x 2048 x 1024    32 MB
    bf16u* att   = (bf16u*)(ws + 118489088);        // 8 x 1024 x 1024    16 MB
    bf16u* out2  = (bf16u*)(ws + 135266304);        // 32768 x 512        32 MB
    // attP (split-K partial logits, 2 x 8 x 1024 x 1024 bf16 = 32 MB) reuses
    // the out2 region: written by stage 2, fully consumed by softmax BEFORE
    // stage 3 overwrites the region with out2.
    bf16u* attP  = out2;

    cvt_x<<<8192, 256, 0, stream>>>(x, xb);
    transpose_cvt<<<512, 256, 0, stream>>>(Wq, WqkvT, 256, 512);
    transpose_cvt<<<1024, 256, 0, stream>>>(Wkv, WqkvT + 512 * 256, 256, 1024);
    transpose_cvt<<<512, 256, 0, stream>>>(Wout, WoutT, 512, 256);

    const float scale = 1.0f / (8.0f * sqrtf(32.0f));

    // stage 1: qkv = xb @ WqkvT^T (M=32768, N=1536, K=256) -> Qt/Kt/Vt2
    gemm8<1><<<dim3(6, 128, 1), 512, 0, stream>>>(
        xb, WqkvT, 256, 256, 0, 0, 0, Qt, Kt, Vt2, 0.f);

    // stage 2 (split-K=2): partial dots, z = half*8 + head -> attP
    gemm8<2><<<dim3(4, 4, 16), 512, 0, stream>>>(
        Qt, Kt, 2048, 1024, 1024, 1024L * 2048, 1024L * 2048, attP, nullptr, nullptr, scale);

    softmax_rows2<<<8192, 256, 0, stream>>>(attP, att);

    // stage 3: per head, out = att_h @ Vt2_h^T (M=1024, N=2048, K=1024) -> out2
    gemm8<3><<<dim3(8, 4, 8), 512, 0, stream>>>(
        att, Vt2, 1024, 1024, 0, 1024L * 1024, 2048L * 1024, out2, nullptr, nullptr, 0.f);

    // stage 4: final = out2 @ WoutT^T + bout (M=32768, N=256, K=512) -> fp32 out
    gemm_out<<<dim3(2, 256, 1), 256, 0, stream>>>(
        out2, WoutT, 512, out, bout);
}